// Round 11
// baseline (508.876 us; speedup 1.0000x reference)
//
#include <hip/hip_runtime.h>
#include <math.h>

typedef unsigned long long u64;
typedef unsigned int u32;

#define N_ROWS 8192
#define DIM 1024
#define KCLS 80
#define KC1 81
#define MCAND 2048
#define TOPK_ 100
#define CMAX 65536
#define ECAP 4096
#define ROWS_CAP 4096
#define RPB 2
#define KSPLIT 4
#define NSPLIT 4
#define NBINS 8192
#define BIN_BASE 125440
#define LCAP 1024
#define SCORE_T 0.05
#define NMS_T 0.5f
#define MAX_COORD_F 1217.0f
#define SCALE_CLAMP_F 4.135166556742356f
#define IMG_W_F 1216.0f
#define IMG_H_F 800.0f

__device__ __forceinline__ int score_bin_f(float p) {
  u32 bits = __float_as_uint(p);
  int b = (int)(bits >> 13) - BIN_BASE;
  return b < 0 ? 0 : (b > NBINS - 1 ? NBINS - 1 : b);
}

__device__ __forceinline__ u64 readlane64(u64 v, int l) {
  u32 lo = __builtin_amdgcn_readlane((u32)v, l);
  u32 hi = __builtin_amdgcn_readlane((u32)(v >> 32), l);
  return ((u64)hi << 32) | (u64)lo;
}

// ---------------------------------------------------------------- init
__global__ void k_init(int* counter, int* ecount, int* rowcnt, int* tbin,
                       int* hist, int* cnt, u32* rowflag,
                       double* selS, u32* selI) {
  int t = blockIdx.x * blockDim.x + threadIdx.x;
  if (t == 0) { *counter = 0; *ecount = 0; *rowcnt = 0; *tbin = 0; }
  if (t < NBINS) hist[t] = 0;
  if (t < N_ROWS) rowflag[t] = 0;
  if (t < ECAP) cnt[t] = 0;
  if (t < MCAND) { selS[t] = -1.0; selI[t] = 0u; }
}

// --------------------------------- f32 cls GEMM, K split 4-way -> partials
#define BK 32
#define XT_STRIDE 34
#define BT_STRIDE 96

__global__ __launch_bounds__(256) void k_gemm_f32(
    const float* __restrict__ x, const float* __restrict__ w,
    float* __restrict__ part)
{
  __shared__ float xt[BK][XT_STRIDE];
  __shared__ float bt[BK][BT_STRIDE];

  const int tid = threadIdx.x;
  const int rb = blockIdx.x * 32;
  const int ks = blockIdx.y;
  const int koff = ks * (DIM / KSPLIT);
  const int cx = tid >> 4;
  const int ry = tid & 15;

  float acc[2][6];
#pragma unroll
  for (int i = 0; i < 2; i++)
#pragma unroll
    for (int j = 0; j < 6; j++) acc[i][j] = 0.0f;

  const int sr  = tid >> 3;
  const int skq = (tid & 7) * 4;

  for (int kt = 0; kt < DIM / KSPLIT; kt += BK) {
    const int kbase = koff + kt;
    float4 xv4 = *(const float4*)(x + (size_t)(rb + sr) * DIM + kbase + skq);
    float breg[12];
#pragma unroll
    for (int q = 0; q < 12; ++q) {
      int e = tid + q * 256;
      int k = e / 96, c = e - k * 96;
      breg[q] = (c < KC1) ? w[(size_t)(kbase + k) * KC1 + c] : 0.0f;
    }
    __syncthreads();
    xt[skq + 0][sr] = xv4.x; xt[skq + 1][sr] = xv4.y;
    xt[skq + 2][sr] = xv4.z; xt[skq + 3][sr] = xv4.w;
#pragma unroll
    for (int q = 0; q < 12; ++q) ((float*)bt)[tid + q * 256] = breg[q];
    __syncthreads();

#pragma unroll
    for (int k = 0; k < BK; ++k) {
      float2 xv = *(const float2*)&xt[k][ry * 2];
      float2 b0 = *(const float2*)&bt[k][cx * 6];
      float2 b1 = *(const float2*)&bt[k][cx * 6 + 2];
      float2 b2 = *(const float2*)&bt[k][cx * 6 + 4];
      float bd[6] = {b0.x, b0.y, b1.x, b1.y, b2.x, b2.y};
#pragma unroll
      for (int j = 0; j < 6; j++) {
        acc[0][j] = fmaf(xv.x, bd[j], acc[0][j]);
        acc[1][j] = fmaf(xv.y, bd[j], acc[1][j]);
      }
    }
    __syncthreads();
  }

#pragma unroll
  for (int i = 0; i < 2; i++) {
    int r = rb + ry * 2 + i;
#pragma unroll
    for (int j = 0; j < 6; j++) {
      int c = cx * 6 + j;
      if (c < KC1) part[((size_t)ks * N_ROWS + r) * KC1 + c] = acc[i][j];
    }
  }
}

// ------------- f32 softmax + approx candidate compact + surely-valid hist
#define NE32 (32 * KC1)         // 2592 floats per slab-tile
__global__ __launch_bounds__(256) void k_softmax32(
    const float* __restrict__ part, const float* __restrict__ bias,
    float* __restrict__ scf, u32* __restrict__ cid,
    int* __restrict__ counter, int* __restrict__ hist)
{
  __shared__ float lgs[NE32];          // summed logits (pre-bias), 10.4 KB
  __shared__ float red[16][32];
  __shared__ float rowM[32];
  __shared__ float rowS[32];
  __shared__ u32 lhist[NBINS / 2];     // packed u16 pairs, 16 KB
  __shared__ float lscf[LCAP];         // 4 KB
  __shared__ u32 lcid[LCAP];           // 4 KB
  __shared__ int lcnt, gbase;
  const int tid = threadIdx.x;
  const int rb = blockIdx.x * 32;
  const int cx = tid >> 4;
  const int ry = tid & 15;

  if (tid == 0) lcnt = 0;
  for (int e = tid; e < NBINS / 2; e += 256) lhist[e] = 0u;

  {
    const float4* p0 = (const float4*)(part + ((size_t)0 * N_ROWS + rb) * KC1);
    const float4* p1 = (const float4*)(part + ((size_t)1 * N_ROWS + rb) * KC1);
    const float4* p2 = (const float4*)(part + ((size_t)2 * N_ROWS + rb) * KC1);
    const float4* p3 = (const float4*)(part + ((size_t)3 * N_ROWS + rb) * KC1);
    float4* dst = (float4*)lgs;
    for (int q = tid; q < NE32 / 4; q += 256) {
      float4 s0 = p0[q], s1 = p1[q], s2 = p2[q], s3 = p3[q];
      float4 t;
      t.x = (s0.x + s1.x) + (s2.x + s3.x);
      t.y = (s0.y + s1.y) + (s2.y + s3.y);
      t.z = (s0.z + s1.z) + (s2.z + s3.z);
      t.w = (s0.w + s1.w) + (s2.w + s3.w);
      dst[q] = t;
    }
  }
  __syncthreads();

  float lg[2][6];
#pragma unroll
  for (int i = 0; i < 2; i++) {
    int rloc = ry * 2 + i;
#pragma unroll
    for (int j = 0; j < 6; j++) {
      int c = cx * 6 + j;
      lg[i][j] = (c < KC1) ? (lgs[rloc * KC1 + c] + bias[c]) : -1e30f;
    }
  }
  float pm[2] = {-1e30f, -1e30f};
#pragma unroll
  for (int i = 0; i < 2; i++)
#pragma unroll
    for (int j = 0; j < 6; j++) pm[i] = fmaxf(pm[i], lg[i][j]);
  red[cx][ry * 2 + 0] = pm[0];
  red[cx][ry * 2 + 1] = pm[1];
  __syncthreads();
  if (tid < 32) {
    float m = -1e30f;
#pragma unroll
    for (int q = 0; q < 16; q++) m = fmaxf(m, red[q][tid]);
    rowM[tid] = m;
  }
  __syncthreads();
  float ps[2] = {0.0f, 0.0f};
#pragma unroll
  for (int i = 0; i < 2; i++) {
    float m = rowM[ry * 2 + i];
#pragma unroll
    for (int j = 0; j < 6; j++) {
      int c = cx * 6 + j;
      if (c < KC1) ps[i] += expf(lg[i][j] - m);
    }
  }
  __syncthreads();
  red[cx][ry * 2 + 0] = ps[0];
  red[cx][ry * 2 + 1] = ps[1];
  __syncthreads();
  if (tid < 32) {
    float s = 0.0f;
#pragma unroll
    for (int q = 0; q < 16; q++) s += red[q][tid];
    rowS[tid] = s;
  }
  __syncthreads();
#pragma unroll
  for (int i = 0; i < 2; i++) {
    int rloc = ry * 2 + i;
    float m = rowM[rloc], s = rowS[rloc];
#pragma unroll
    for (int j = 0; j < 6; j++) {
      int c = cx * 6 + j;
      if (c < KCLS) {
        float p = expf(lg[i][j] - m) / s;
        if (p > 0.0485f) {                     // superset of exact p>0.05
          int pos = atomicAdd(&lcnt, 1);       // LDS atomic (per-CU, fast)
          u32 idx = (u32)((rb + rloc) * KCLS + c);
          if (pos < LCAP) { lscf[pos] = p; lcid[pos] = idx; }
          else {                               // overflow fallback (rare)
            int g = atomicAdd(counter, 1);
            if (g < CMAX) { scf[g] = p; cid[g] = idx; }
          }
        }
        if (p > 0.051f) {                      // surely exact-valid
          int b = score_bin_f(p);
          atomicAdd(&lhist[b >> 1], 1u << ((b & 1) * 16));
        }
      }
    }
  }
  __syncthreads();
  if (tid == 0) {
    int n = min(lcnt, LCAP);
    gbase = atomicAdd(counter, n);
  }
  __syncthreads();
  {
    int n = min(lcnt, LCAP);
    for (int e = tid; e < n; e += 256) {
      int g = gbase + e;
      if (g < CMAX) { scf[g] = lscf[e]; cid[g] = lcid[e]; }
    }
  }
  for (int q = tid; q < NBINS / 2; q += 256) {
    u32 v = lhist[q];
    if (v) {
      u32 lo = v & 0xFFFFu, hi = v >> 16;
      if (lo) atomicAdd(&hist[q * 2 + 0], (int)lo);
      if (hi) atomicAdd(&hist[q * 2 + 1], (int)hi);
    }
  }
}

// -------------------------------------- find threshold bin (suffix >= MCAND)
__global__ __launch_bounds__(256) void k_thresh(
    const int* __restrict__ hist, int* __restrict__ tbin)
{
  __shared__ int h[NBINS];
  __shared__ int segsum[256];
  __shared__ int segsuf[256];
  const int tid = threadIdx.x;
  for (int e = tid; e < NBINS; e += 256) h[e] = hist[e];
  __syncthreads();
  int s = 0;
#pragma unroll
  for (int q = 0; q < NBINS / 256; ++q) s += h[tid * (NBINS / 256) + q];
  segsum[tid] = s;
  __syncthreads();
  if (tid == 0) {
    int run = 0;
    for (int t = 255; t >= 0; --t) { segsuf[t] = run; run += segsum[t]; }
  }
  __syncthreads();
  int run = segsuf[tid];
  if (run < MCAND) {
    const int lo = tid * (NBINS / 256);
    for (int b = lo + NBINS / 256 - 1; b >= lo; --b) {
      run += h[b];
      if (run >= MCAND) { *tbin = b; break; }
    }
  }
}

// -------------------- superset: approx-bin >= T-6 -> element list + row flags
__global__ __launch_bounds__(256) void k_superset(
    const float* __restrict__ scf, const u32* __restrict__ cid,
    const int* __restrict__ counter, const int* __restrict__ tbin,
    u32* __restrict__ elist, int* __restrict__ ecount, u32* __restrict__ rowflag)
{
  int C = *counter; if (C > CMAX) C = CMAX;
  int TM = *tbin - 6; if (TM < 0) TM = 0;
  int e = blockIdx.x * 256 + threadIdx.x;
  const int lane = threadIdx.x & 63;
  bool pred = false;
  float p = 0.0f;
  if (e < C) {
    p = scf[e];
    pred = (score_bin_f(p) >= TM);
  }
  u64 m = __ballot(pred);
  if (m) {
    int leader = __ffsll((long long)m) - 1;
    int base = 0;
    if (lane == leader) base = atomicAdd(ecount, (int)__popcll(m));
    base = __shfl(base, leader);
    if (pred) {
      int j = base + (int)__popcll(m & ((lane == 63) ? ~0ull >> 1 : ((1ull << lane) - 1)));
      if (j < ECAP) {
        u32 idx = cid[e];
        elist[j] = idx;
        rowflag[idx / KCLS] = 1u;
      }
    }
  }
}

// ---------------------------------------------- compact flagged rows to list
__global__ __launch_bounds__(256) void k_rowlist(
    const u32* __restrict__ rowflag, int* __restrict__ rowslot,
    u32* __restrict__ rowlist, int* __restrict__ rowcnt)
{
  int r = blockIdx.x * 256 + threadIdx.x;
  const int lane = threadIdx.x & 63;
  bool pred = (r < N_ROWS) && rowflag[r];
  u64 m = __ballot(pred);
  if (m) {
    int leader = __ffsll((long long)m) - 1;
    int base = 0;
    if (lane == leader) base = atomicAdd(rowcnt, (int)__popcll(m));
    base = __shfl(base, leader);
    if (pred) {
      int s = base + (int)__popcll(m & ((lane == 63) ? ~0ull >> 1 : ((1ull << lane) - 1)));
      if (s < ROWS_CAP) { rowslot[r] = s; rowlist[s] = (u32)r; }
    }
  }
}

// ---- exact f64 logits+softmax for flagged rows (RPB rows/block, coalesced w)
__global__ __launch_bounds__(128) void k_exact_rows(
    const u32* __restrict__ rowlist, const int* __restrict__ rowcnt,
    const float* __restrict__ x, const float* __restrict__ w,
    const float* __restrict__ bias, double* __restrict__ prow)
{
  __shared__ float xr[RPB][DIM];
  __shared__ double lg[RPB][KC1];
  __shared__ double mv[RPB], sv[RPB];
  int rc = *rowcnt; if (rc > ROWS_CAP) rc = ROWS_CAP;
  const int base = blockIdx.x * RPB;
  if (base >= rc) return;
  const int tid = threadIdx.x;
  const int nr = min(RPB, rc - base);

  for (int rr = 0; rr < nr; ++rr) {
    const float4* xs = (const float4*)(x + (size_t)rowlist[base + rr] * DIM);
    float4* dst = (float4*)xr[rr];
#pragma unroll
    for (int q = 0; q < DIM / 4 / 128; ++q) dst[tid + q * 128] = xs[tid + q * 128];
  }
  __syncthreads();

  if (tid < KC1) {
    const int c = tid;
    double a0 = 0.0, a1 = 0.0;
    for (int k = 0; k < DIM; k += 4) {
      float4 x0 = *(const float4*)&xr[0][k];
      float4 x1 = *(const float4*)&xr[1][k];
      float w0 = w[(size_t)k * KC1 + c];
      float w1 = w[(size_t)(k + 1) * KC1 + c];
      float w2 = w[(size_t)(k + 2) * KC1 + c];
      float w3 = w[(size_t)(k + 3) * KC1 + c];
      a0 = fma((double)x0.x, (double)w0, a0);
      a0 = fma((double)x0.y, (double)w1, a0);
      a0 = fma((double)x0.z, (double)w2, a0);
      a0 = fma((double)x0.w, (double)w3, a0);
      a1 = fma((double)x1.x, (double)w0, a1);
      a1 = fma((double)x1.y, (double)w1, a1);
      a1 = fma((double)x1.z, (double)w2, a1);
      a1 = fma((double)x1.w, (double)w3, a1);
    }
    lg[0][c] = a0 + (double)bias[c];
    lg[1][c] = a1 + (double)bias[c];
  }
  __syncthreads();
  if (tid < nr) {
    double m = -1e300;
    for (int c2 = 0; c2 < KC1; ++c2) m = fmax(m, lg[tid][c2]);
    mv[tid] = m;
  }
  __syncthreads();
  if (tid < KC1) {
    for (int rr = 0; rr < nr; ++rr) lg[rr][tid] = exp(lg[rr][tid] - mv[rr]);
  }
  __syncthreads();
  if (tid < nr) {
    double s = 0.0;
    for (int c2 = 0; c2 < KC1; ++c2) s += lg[tid][c2];
    sv[tid] = s;
  }
  __syncthreads();
  if (tid < KC1) {
    for (int rr = 0; rr < nr; ++rr)
      prow[(size_t)(base + rr) * KC1 + tid] = lg[rr][tid] / sv[rr];
  }
}

// ------------------------- build exact (score, idx) arrays for the superset
__global__ __launch_bounds__(256) void k_build(
    const u32* __restrict__ elist, const int* __restrict__ ecount,
    const int* __restrict__ rowslot, const double* __restrict__ prow,
    double* __restrict__ ssc, u32* __restrict__ sid)
{
  int E = *ecount; if (E > ECAP) E = ECAP;
  int e = blockIdx.x * 256 + threadIdx.x;
  if (e < E) {
    u32 idx = elist[e];
    int row = (int)(idx / KCLS);
    int cls = (int)(idx - (u32)row * KCLS);
    double p = prow[(size_t)rowslot[row] * KC1 + cls];
    ssc[e] = (p > SCORE_T) ? p : -1.0;
    sid[e] = idx;
  }
}

// --------------------------- exact rank-count among superset (j-range split)
__global__ __launch_bounds__(256) void k_rank(
    const double* __restrict__ ssc, const u32* __restrict__ sid,
    const int* __restrict__ ecount, int* __restrict__ cnt)
{
  __shared__ double lsc[2048];
  __shared__ u32 lid[2048];
  int S = *ecount; if (S > ECAP) S = ECAP;
  const int i = blockIdx.x * 256 + threadIdx.x;
  if (blockIdx.x * 256 >= S) return;
  const double si = (i < S) ? ssc[i] : -2.0;
  const u32 ii = (i < S) ? sid[i] : 0u;
  const int seg = (S + NSPLIT - 1) / NSPLIT;
  const int jlo = blockIdx.y * seg;
  const int jhi = min(S, jlo + seg);
  int c = 0;
  for (int base = jlo; base < jhi; base += 2048) {
    const int n = min(2048, jhi - base);
    __syncthreads();
    for (int e = threadIdx.x; e < n; e += 256) { lsc[e] = ssc[base + e]; lid[e] = sid[base + e]; }
    __syncthreads();
    if (i < S) {
      for (int j = 0; j < n; ++j) {
        double sj = lsc[j];
        c += (sj > si || (sj == si && lid[j] < ii)) ? 1 : 0;
      }
    }
  }
  if (i < S && c > 0) atomicAdd(&cnt[i], c);
}

// ----------------------------------------------------- scatter by final rank
__global__ __launch_bounds__(256) void k_scatter(
    const double* __restrict__ ssc, const u32* __restrict__ sid,
    const int* __restrict__ ecount, const int* __restrict__ cnt,
    double* __restrict__ selS, u32* __restrict__ selI)
{
  int S = *ecount; if (S > ECAP) S = ECAP;
  const int i = blockIdx.x * 256 + threadIdx.x;
  if (i < S) {
    int c = cnt[i];
    if (c < MCAND) { selS[c] = ssc[i]; selI[c] = sid[i]; }
  }
}

// -------------------------------- per-candidate bbox delta dot + decode + clip
__global__ __launch_bounds__(256) void k_gather_decode(
    const double* __restrict__ selS, const u32* __restrict__ selI,
    const float* __restrict__ x, const float* __restrict__ bw,
    const float* __restrict__ bbias, const float* __restrict__ proposals,
    float4* __restrict__ dbox, float4* __restrict__ obox,
    float* __restrict__ areav, float* __restrict__ scorev,
    int* __restrict__ clsv, int* __restrict__ validv)
{
  __shared__ double wred[4][4];
  const int r = blockIdx.x;
  const double s = selS[r];
  const u32 idx = selI[r];
  const int row = (int)(idx / 80u);
  const int cls = (int)(idx - (u32)row * 80u);

  const float* xr = x + (size_t)row * DIM;
  const float4* bwv = (const float4*)bw;
  double a0 = 0, a1 = 0, a2 = 0, a3 = 0;
  for (int k = threadIdx.x; k < DIM; k += 256) {
    double xv = (double)xr[k];
    float4 wv = bwv[(size_t)k * 80 + cls];
    a0 = fma(xv, (double)wv.x, a0);
    a1 = fma(xv, (double)wv.y, a1);
    a2 = fma(xv, (double)wv.z, a2);
    a3 = fma(xv, (double)wv.w, a3);
  }
#pragma unroll
  for (int off = 32; off > 0; off >>= 1) {
    a0 += __shfl_down(a0, off);
    a1 += __shfl_down(a1, off);
    a2 += __shfl_down(a2, off);
    a3 += __shfl_down(a3, off);
  }
  int lane = threadIdx.x & 63, wid = threadIdx.x >> 6;
  if (lane == 0) { wred[wid][0] = a0; wred[wid][1] = a1; wred[wid][2] = a2; wred[wid][3] = a3; }
  __syncthreads();
  if (threadIdx.x == 0) {
    double d0 = wred[0][0] + wred[1][0] + wred[2][0] + wred[3][0] + (double)bbias[cls * 4 + 0];
    double d1 = wred[0][1] + wred[1][1] + wred[2][1] + wred[3][1] + (double)bbias[cls * 4 + 1];
    double d2 = wred[0][2] + wred[1][2] + wred[2][2] + wred[3][2] + (double)bbias[cls * 4 + 2];
    double d3 = wred[0][3] + wred[1][3] + wred[2][3] + wred[3][3] + (double)bbias[cls * 4 + 3];
    float4 p = ((const float4*)proposals)[row];
    float w = p.z - p.x, h = p.w - p.y;
    float cxx = p.x + 0.5f * w, cyy = p.y + 0.5f * h;
    float dx = (float)d0 / 10.0f;
    float dy = (float)d1 / 10.0f;
    float dw = fminf((float)d2 / 5.0f, SCALE_CLAMP_F);
    float dh = fminf((float)d3 / 5.0f, SCALE_CLAMP_F);
    float pcx = dx * w + cxx, pcy = dy * h + cyy;
    float pw = expf(dw) * w, ph = expf(dh) * h;
    float x1 = pcx - 0.5f * pw, y1 = pcy - 0.5f * ph;
    float x2 = pcx + 0.5f * pw, y2 = pcy + 0.5f * ph;
    x1 = fminf(fmaxf(x1, 0.0f), IMG_W_F);
    x2 = fminf(fmaxf(x2, 0.0f), IMG_W_F);
    y1 = fminf(fmaxf(y1, 0.0f), IMG_H_F);
    y2 = fminf(fmaxf(y2, 0.0f), IMG_H_F);
    float4 db = {x1, y1, x2, y2};
    dbox[r] = db;
    float ofs = (float)cls * MAX_COORD_F;
    float4 ob = {x1 + ofs, y1 + ofs, x2 + ofs, y2 + ofs};
    obox[r] = ob;
    areav[r] = (ob.z - ob.x) * (ob.w - ob.y);
    scorev[r] = (float)s;
    clsv[r] = cls;
    validv[r] = (s > SCORE_T) ? 1 : 0;
  }
}

// --------------------- pairwise suppression bitmask (TRANSPOSED layout)
// maskT[w * MCAND/64... : column-word w, indexed by row i: maskT[w*2048 + i]
__global__ __launch_bounds__(256) void k_nms_mask(
    const float4* __restrict__ obox, const float* __restrict__ areav,
    u64* __restrict__ maskT)
{
  __shared__ float4 sb[MCAND];
  __shared__ float sa[MCAND];
  const int i = blockIdx.x;
  for (int e = threadIdx.x; e < MCAND; e += 256) { sb[e] = obox[e]; sa[e] = areav[e]; }
  __syncthreads();
  float4 bi = sb[i];
  float ai = sa[i];
  int lane = threadIdx.x & 63, wid = threadIdx.x >> 6;
#pragma unroll
  for (int it = 0; it < MCAND / 256; ++it) {
    int j = it * 256 + threadIdx.x;
    float4 bj = sb[j];
    float xx1 = fmaxf(bi.x, bj.x);
    float yy1 = fmaxf(bi.y, bj.y);
    float xx2 = fminf(bi.z, bj.z);
    float yy2 = fminf(bi.w, bj.w);
    float inter = fmaxf(xx2 - xx1, 0.0f) * fmaxf(yy2 - yy1, 0.0f);
    float uni = ai + sa[j] - inter;
    float iou = inter / fmaxf(uni, 1e-9f);
    bool pred = (iou > NMS_T) && (j > i);
    u64 b = __ballot(pred);
    if (lane == 0) maskT[(size_t)(it * 4 + wid) * MCAND + i] = b;
  }
}

// ---- sequential suppression scan: ONE wave, column-gather, no LDS/barriers
// sup word c = OR{maskT[c][i] : alive i < 64c}; then branch-free intra resolve
__global__ __launch_bounds__(64) void k_nms_reduce(
    const u64* __restrict__ maskT, const int* __restrict__ validv,
    int* __restrict__ keep)
{
  const int lane = threadIdx.x;  // 0..63

  // validw: lane k holds valid word k (k<32)
  u64 validw = 0;
  for (int k = 0; k < 32; ++k) {
    u64 b = __ballot(validv[k * 64 + lane] != 0);
    validw = (lane == k) ? b : validw;
  }

  u64 alivew = 0;   // lane k holds alive word k
  u64 supw = 0;     // lane k holds final sup word k

  for (int c = 0; c < 32; ++c) {
    const u64* col = maskT + (size_t)c * MCAND;
    // gather incoming suppression: alive rows i < 64c, column word c
    u64 acc = 0;
    for (int t0 = 0; t0 < c; t0 += 8) {
      const int n = min(8, c - t0);
      u64 r[8];
      for (int q = 0; q < n; ++q) r[q] = col[(t0 + q) * 64 + lane];
      for (int q = 0; q < n; ++q) {
        u64 aw = readlane64(alivew, t0 + q);        // wave-uniform
        u64 bit = (aw >> lane) & 1ull;              // this lane's row alive?
        acc |= r[q] & ((u64)0 - bit);
      }
    }
    u64 d = col[(size_t)c * 64 + lane];             // diagonal word (row 64c+lane)
    // OR-reduce acc across 64 lanes
    acc |= (u64)__shfl_xor((long long)acc, 1);
    acc |= (u64)__shfl_xor((long long)acc, 2);
    acc |= (u64)__shfl_xor((long long)acc, 4);
    acc |= (u64)__shfl_xor((long long)acc, 8);
    acc |= (u64)__shfl_xor((long long)acc, 16);
    acc |= (u64)__shfl_xor((long long)acc, 32);
    u64 s_sup = acc;                                 // wave-uniform now
    u64 s_val = readlane64(validw, c);
    // branch-free sequential intra-chunk resolve (row b has only bits > b)
    u64 aliveM = 0;
#pragma unroll
    for (int b = 0; b < 64; ++b) {
      u32 rhi = __builtin_amdgcn_readlane((u32)(d >> 32), b);
      u32 rlo = (b < 31) ? __builtin_amdgcn_readlane((u32)d, b) : 0u;
      u64 row = ((u64)rhi << 32) | (u64)rlo;
      u64 act = ((s_val >> b) & 1ull) & (~(s_sup >> b) & 1ull);
      s_sup |= row & ((u64)0 - act);
      aliveM |= act << b;
    }
    alivew = (lane == c) ? aliveM : alivew;
    supw   = (lane == c) ? s_sup  : supw;
  }

  for (int k = 0; k < 32; ++k) {
    u64 s = readlane64(supw, k);
    int e = k * 64 + lane;
    int sb = (int)((s >> lane) & 1ull);
    keep[e] = (validv[e] && !sb) ? 1 : 0;
  }
}

// ------------------------------------------------ final top-100 + write outputs
__global__ __launch_bounds__(256) void k_finalize(
    const int* __restrict__ keep, const float4* __restrict__ dbox,
    const float* __restrict__ scorev, const int* __restrict__ clsv,
    float* __restrict__ out)
{
  __shared__ short fidx[TOPK_];
  __shared__ char ksh[MCAND];
  const int tid = threadIdx.x;
  for (int e = tid; e < MCAND; e += 256) ksh[e] = (char)keep[e];
  __syncthreads();
  if (tid == 0) {
    int cnt = 0;
    for (int r = 0; r < MCAND && cnt < TOPK_; ++r) if (ksh[r]) fidx[cnt++] = (short)r;
    for (int r = 0; r < MCAND && cnt < TOPK_; ++r) if (!ksh[r]) fidx[cnt++] = (short)r;
  }
  __syncthreads();
  if (tid < TOPK_) {
    int r = fidx[tid];
    float4 b = dbox[r];
    out[tid * 4 + 0] = b.x; out[tid * 4 + 1] = b.y;
    out[tid * 4 + 2] = b.z; out[tid * 4 + 3] = b.w;
    int kp = ksh[r];
    out[400 + tid] = kp ? scorev[r] : -1.0f;
    out[500 + tid] = (float)clsv[r];
    out[600 + tid] = kp ? 1.0f : 0.0f;
  }
}

// ----------------------------------------------------------------------------
extern "C" void kernel_launch(void* const* d_in, const int* in_sizes, int n_in,
                              void* d_out, int out_size, void* d_ws, size_t ws_size,
                              hipStream_t stream) {
  const float* x         = (const float*)d_in[0];
  const float* cls_w     = (const float*)d_in[1];
  const float* cls_b     = (const float*)d_in[2];
  const float* bbox_w    = (const float*)d_in[3];
  const float* bbox_b    = (const float*)d_in[4];
  const float* proposals = (const float*)d_in[5];
  float* out = (float*)d_out;

  char* ws = (char*)d_ws;
  size_t off = 0;
  float*  part  = (float*)(ws + off);  off += (size_t)KSPLIT * N_ROWS * KC1 * 4;
  float*  scf   = (float*)(ws + off);  off += (size_t)CMAX * 4;
  u32*    cid   = (u32*)(ws + off);    off += (size_t)CMAX * 4;
  int*    hist  = (int*)(ws + off);    off += (size_t)NBINS * 4;
  u32*    rowflag = (u32*)(ws + off);  off += (size_t)N_ROWS * 4;
  int*    rowslot = (int*)(ws + off);  off += (size_t)N_ROWS * 4;
  u32*    rowlist = (u32*)(ws + off);  off += (size_t)ROWS_CAP * 4;
  u32*    elist = (u32*)(ws + off);    off += (size_t)ECAP * 4;
  double* prow  = (double*)(ws + off); off += (size_t)ROWS_CAP * KC1 * 8;
  double* ssc   = (double*)(ws + off); off += (size_t)ECAP * 8;
  u32*    sid   = (u32*)(ws + off);    off += (size_t)ECAP * 4;
  int*    cnt   = (int*)(ws + off);    off += (size_t)ECAP * 4;
  double* selS  = (double*)(ws + off); off += (size_t)MCAND * 8;
  u32*    selI  = (u32*)(ws + off);    off += (size_t)MCAND * 4;
  off = (off + 15) & ~(size_t)15;
  int*    counter = (int*)(ws + off);  off += 16;
  int*    ecount  = (int*)(ws + off);  off += 16;
  int*    rowcnt  = (int*)(ws + off);  off += 16;
  int*    tbin    = (int*)(ws + off);  off += 16;
  float4* dbox  = (float4*)(ws + off); off += (size_t)MCAND * 16;
  float4* obox  = (float4*)(ws + off); off += (size_t)MCAND * 16;
  float*  areav = (float*)(ws + off);  off += (size_t)MCAND * 4;
  float*  scorev= (float*)(ws + off);  off += (size_t)MCAND * 4;
  int*    clsv  = (int*)(ws + off);    off += (size_t)MCAND * 4;
  int*    validv= (int*)(ws + off);    off += (size_t)MCAND * 4;
  int*    keep  = (int*)(ws + off);    off += (size_t)MCAND * 4;
  off = (off + 15) & ~(size_t)15;
  u64*    maskT = (u64*)(ws + off);    off += (size_t)MCAND * 32 * 8;

  k_init<<<N_ROWS / 256, 256, 0, stream>>>(counter, ecount, rowcnt, tbin, hist,
                                           cnt, rowflag, selS, selI);
  k_gemm_f32<<<dim3(N_ROWS / 32, KSPLIT), 256, 0, stream>>>(x, cls_w, part);
  k_softmax32<<<N_ROWS / 32, 256, 0, stream>>>(part, cls_b, scf, cid, counter, hist);
  k_thresh<<<1, 256, 0, stream>>>(hist, tbin);
  k_superset<<<CMAX / 256, 256, 0, stream>>>(scf, cid, counter, tbin, elist, ecount, rowflag);
  k_rowlist<<<N_ROWS / 256, 256, 0, stream>>>(rowflag, rowslot, rowlist, rowcnt);
  k_exact_rows<<<ROWS_CAP / RPB, 128, 0, stream>>>(rowlist, rowcnt, x, cls_w, cls_b, prow);
  k_build<<<ECAP / 256, 256, 0, stream>>>(elist, ecount, rowslot, prow, ssc, sid);
  k_rank<<<dim3(ECAP / 256, NSPLIT), 256, 0, stream>>>(ssc, sid, ecount, cnt);
  k_scatter<<<ECAP / 256, 256, 0, stream>>>(ssc, sid, ecount, cnt, selS, selI);
  k_gather_decode<<<MCAND, 256, 0, stream>>>(selS, selI, x, bbox_w, bbox_b, proposals,
                                             dbox, obox, areav, scorev, clsv, validv);
  k_nms_mask<<<MCAND, 256, 0, stream>>>(obox, areav, maskT);
  k_nms_reduce<<<1, 64, 0, stream>>>(maskT, validv, keep);
  k_finalize<<<1, 256, 0, stream>>>(keep, dbox, scorev, clsv, out);
}

// Round 12
// 291.464 us; speedup vs baseline: 1.7459x; 1.7459x over previous
//
#include <hip/hip_runtime.h>
#include <math.h>

typedef unsigned long long u64;
typedef unsigned int u32;

#define N_ROWS 8192
#define DIM 1024
#define KCLS 80
#define KC1 81
#define MCAND 2048
#define TOPK_ 100
#define CMAX 65536
#define ECAP 4096
#define ROWS_CAP 4096
#define RPB 2
#define KSPLIT 4
#define NSPLIT 4
#define NBINS 8192
#define BIN_BASE 125440
#define LCAP 1024
#define SCORE_T 0.05
#define NMS_T 0.5f
#define MAX_COORD_F 1217.0f
#define SCALE_CLAMP_F 4.135166556742356f
#define IMG_W_F 1216.0f
#define IMG_H_F 800.0f

__device__ __forceinline__ int score_bin_f(float p) {
  u32 bits = __float_as_uint(p);
  int b = (int)(bits >> 13) - BIN_BASE;
  return b < 0 ? 0 : (b > NBINS - 1 ? NBINS - 1 : b);
}

__device__ __forceinline__ u64 readlane64(u64 v, int l) {
  u32 lo = __builtin_amdgcn_readlane((u32)v, l);
  u32 hi = __builtin_amdgcn_readlane((u32)(v >> 32), l);
  return ((u64)hi << 32) | (u64)lo;
}

// ---------------------------------------------------------------- init
__global__ void k_init(int* counter, int* ecount, int* rowcnt, int* tbin,
                       int* hist, int* cnt, u32* rowflag,
                       double* selS, u32* selI) {
  int t = blockIdx.x * blockDim.x + threadIdx.x;
  if (t == 0) { *counter = 0; *ecount = 0; *rowcnt = 0; *tbin = 0; }
  if (t < NBINS) hist[t] = 0;
  if (t < N_ROWS) rowflag[t] = 0;
  if (t < ECAP) cnt[t] = 0;
  if (t < MCAND) { selS[t] = -1.0; selI[t] = 0u; }
}

// --------------------------------- f32 cls GEMM, K split 4-way -> partials
#define BK 32
#define XT_STRIDE 34
#define BT_STRIDE 96

__global__ __launch_bounds__(256) void k_gemm_f32(
    const float* __restrict__ x, const float* __restrict__ w,
    float* __restrict__ part)
{
  __shared__ float xt[BK][XT_STRIDE];
  __shared__ float bt[BK][BT_STRIDE];

  const int tid = threadIdx.x;
  const int rb = blockIdx.x * 32;
  const int ks = blockIdx.y;
  const int koff = ks * (DIM / KSPLIT);
  const int cx = tid >> 4;
  const int ry = tid & 15;

  float acc[2][6];
#pragma unroll
  for (int i = 0; i < 2; i++)
#pragma unroll
    for (int j = 0; j < 6; j++) acc[i][j] = 0.0f;

  const int sr  = tid >> 3;
  const int skq = (tid & 7) * 4;

  for (int kt = 0; kt < DIM / KSPLIT; kt += BK) {
    const int kbase = koff + kt;
    float4 xv4 = *(const float4*)(x + (size_t)(rb + sr) * DIM + kbase + skq);
    float breg[12];
#pragma unroll
    for (int q = 0; q < 12; ++q) {
      int e = tid + q * 256;
      int k = e / 96, c = e - k * 96;
      breg[q] = (c < KC1) ? w[(size_t)(kbase + k) * KC1 + c] : 0.0f;
    }
    __syncthreads();
    xt[skq + 0][sr] = xv4.x; xt[skq + 1][sr] = xv4.y;
    xt[skq + 2][sr] = xv4.z; xt[skq + 3][sr] = xv4.w;
#pragma unroll
    for (int q = 0; q < 12; ++q) ((float*)bt)[tid + q * 256] = breg[q];
    __syncthreads();

#pragma unroll
    for (int k = 0; k < BK; ++k) {
      float2 xv = *(const float2*)&xt[k][ry * 2];
      float2 b0 = *(const float2*)&bt[k][cx * 6];
      float2 b1 = *(const float2*)&bt[k][cx * 6 + 2];
      float2 b2 = *(const float2*)&bt[k][cx * 6 + 4];
      float bd[6] = {b0.x, b0.y, b1.x, b1.y, b2.x, b2.y};
#pragma unroll
      for (int j = 0; j < 6; j++) {
        acc[0][j] = fmaf(xv.x, bd[j], acc[0][j]);
        acc[1][j] = fmaf(xv.y, bd[j], acc[1][j]);
      }
    }
    __syncthreads();
  }

#pragma unroll
  for (int i = 0; i < 2; i++) {
    int r = rb + ry * 2 + i;
#pragma unroll
    for (int j = 0; j < 6; j++) {
      int c = cx * 6 + j;
      if (c < KC1) part[((size_t)ks * N_ROWS + r) * KC1 + c] = acc[i][j];
    }
  }
}

// ------------- f32 softmax + approx candidate compact + surely-valid hist
#define NE32 (32 * KC1)         // 2592 floats per slab-tile
__global__ __launch_bounds__(256) void k_softmax32(
    const float* __restrict__ part, const float* __restrict__ bias,
    float* __restrict__ scf, u32* __restrict__ cid,
    int* __restrict__ counter, int* __restrict__ hist)
{
  __shared__ float lgs[NE32];          // summed logits (pre-bias), 10.4 KB
  __shared__ float red[16][32];
  __shared__ float rowM[32];
  __shared__ float rowS[32];
  __shared__ u32 lhist[NBINS / 2];     // packed u16 pairs, 16 KB
  __shared__ float lscf[LCAP];         // 4 KB
  __shared__ u32 lcid[LCAP];           // 4 KB
  __shared__ int lcnt, gbase;
  const int tid = threadIdx.x;
  const int rb = blockIdx.x * 32;
  const int cx = tid >> 4;
  const int ry = tid & 15;

  if (tid == 0) lcnt = 0;
  for (int e = tid; e < NBINS / 2; e += 256) lhist[e] = 0u;

  {
    const float4* p0 = (const float4*)(part + ((size_t)0 * N_ROWS + rb) * KC1);
    const float4* p1 = (const float4*)(part + ((size_t)1 * N_ROWS + rb) * KC1);
    const float4* p2 = (const float4*)(part + ((size_t)2 * N_ROWS + rb) * KC1);
    const float4* p3 = (const float4*)(part + ((size_t)3 * N_ROWS + rb) * KC1);
    float4* dst = (float4*)lgs;
    for (int q = tid; q < NE32 / 4; q += 256) {
      float4 s0 = p0[q], s1 = p1[q], s2 = p2[q], s3 = p3[q];
      float4 t;
      t.x = (s0.x + s1.x) + (s2.x + s3.x);
      t.y = (s0.y + s1.y) + (s2.y + s3.y);
      t.z = (s0.z + s1.z) + (s2.z + s3.z);
      t.w = (s0.w + s1.w) + (s2.w + s3.w);
      dst[q] = t;
    }
  }
  __syncthreads();

  float lg[2][6];
#pragma unroll
  for (int i = 0; i < 2; i++) {
    int rloc = ry * 2 + i;
#pragma unroll
    for (int j = 0; j < 6; j++) {
      int c = cx * 6 + j;
      lg[i][j] = (c < KC1) ? (lgs[rloc * KC1 + c] + bias[c]) : -1e30f;
    }
  }
  float pm[2] = {-1e30f, -1e30f};
#pragma unroll
  for (int i = 0; i < 2; i++)
#pragma unroll
    for (int j = 0; j < 6; j++) pm[i] = fmaxf(pm[i], lg[i][j]);
  red[cx][ry * 2 + 0] = pm[0];
  red[cx][ry * 2 + 1] = pm[1];
  __syncthreads();
  if (tid < 32) {
    float m = -1e30f;
#pragma unroll
    for (int q = 0; q < 16; q++) m = fmaxf(m, red[q][tid]);
    rowM[tid] = m;
  }
  __syncthreads();
  float ps[2] = {0.0f, 0.0f};
#pragma unroll
  for (int i = 0; i < 2; i++) {
    float m = rowM[ry * 2 + i];
#pragma unroll
    for (int j = 0; j < 6; j++) {
      int c = cx * 6 + j;
      if (c < KC1) ps[i] += expf(lg[i][j] - m);
    }
  }
  __syncthreads();
  red[cx][ry * 2 + 0] = ps[0];
  red[cx][ry * 2 + 1] = ps[1];
  __syncthreads();
  if (tid < 32) {
    float s = 0.0f;
#pragma unroll
    for (int q = 0; q < 16; q++) s += red[q][tid];
    rowS[tid] = s;
  }
  __syncthreads();
#pragma unroll
  for (int i = 0; i < 2; i++) {
    int rloc = ry * 2 + i;
    float m = rowM[rloc], s = rowS[rloc];
#pragma unroll
    for (int j = 0; j < 6; j++) {
      int c = cx * 6 + j;
      if (c < KCLS) {
        float p = expf(lg[i][j] - m) / s;
        if (p > 0.0485f) {                     // superset of exact p>0.05
          int pos = atomicAdd(&lcnt, 1);       // LDS atomic (per-CU, fast)
          u32 idx = (u32)((rb + rloc) * KCLS + c);
          if (pos < LCAP) { lscf[pos] = p; lcid[pos] = idx; }
          else {                               // overflow fallback (rare)
            int g = atomicAdd(counter, 1);
            if (g < CMAX) { scf[g] = p; cid[g] = idx; }
          }
        }
        if (p > 0.051f) {                      // surely exact-valid
          int b = score_bin_f(p);
          atomicAdd(&lhist[b >> 1], 1u << ((b & 1) * 16));
        }
      }
    }
  }
  __syncthreads();
  if (tid == 0) {
    int n = min(lcnt, LCAP);
    gbase = atomicAdd(counter, n);
  }
  __syncthreads();
  {
    int n = min(lcnt, LCAP);
    for (int e = tid; e < n; e += 256) {
      int g = gbase + e;
      if (g < CMAX) { scf[g] = lscf[e]; cid[g] = lcid[e]; }
    }
  }
  for (int q = tid; q < NBINS / 2; q += 256) {
    u32 v = lhist[q];
    if (v) {
      u32 lo = v & 0xFFFFu, hi = v >> 16;
      if (lo) atomicAdd(&hist[q * 2 + 0], (int)lo);
      if (hi) atomicAdd(&hist[q * 2 + 1], (int)hi);
    }
  }
}

// -------------------------------------- find threshold bin (suffix >= MCAND)
__global__ __launch_bounds__(256) void k_thresh(
    const int* __restrict__ hist, int* __restrict__ tbin)
{
  __shared__ int h[NBINS];
  __shared__ int segsum[256];
  __shared__ int segsuf[256];
  const int tid = threadIdx.x;
  for (int e = tid; e < NBINS; e += 256) h[e] = hist[e];
  __syncthreads();
  int s = 0;
#pragma unroll
  for (int q = 0; q < NBINS / 256; ++q) s += h[tid * (NBINS / 256) + q];
  segsum[tid] = s;
  __syncthreads();
  if (tid == 0) {
    int run = 0;
    for (int t = 255; t >= 0; --t) { segsuf[t] = run; run += segsum[t]; }
  }
  __syncthreads();
  int run = segsuf[tid];
  if (run < MCAND) {
    const int lo = tid * (NBINS / 256);
    for (int b = lo + NBINS / 256 - 1; b >= lo; --b) {
      run += h[b];
      if (run >= MCAND) { *tbin = b; break; }
    }
  }
}

// -------------------- superset: approx-bin >= T-6 -> element list + row flags
__global__ __launch_bounds__(256) void k_superset(
    const float* __restrict__ scf, const u32* __restrict__ cid,
    const int* __restrict__ counter, const int* __restrict__ tbin,
    u32* __restrict__ elist, int* __restrict__ ecount, u32* __restrict__ rowflag)
{
  int C = *counter; if (C > CMAX) C = CMAX;
  int TM = *tbin - 6; if (TM < 0) TM = 0;
  int e = blockIdx.x * 256 + threadIdx.x;
  const int lane = threadIdx.x & 63;
  bool pred = false;
  float p = 0.0f;
  if (e < C) {
    p = scf[e];
    pred = (score_bin_f(p) >= TM);
  }
  u64 m = __ballot(pred);
  if (m) {
    int leader = __ffsll((long long)m) - 1;
    int base = 0;
    if (lane == leader) base = atomicAdd(ecount, (int)__popcll(m));
    base = __shfl(base, leader);
    if (pred) {
      int j = base + (int)__popcll(m & ((lane == 63) ? ~0ull >> 1 : ((1ull << lane) - 1)));
      if (j < ECAP) {
        u32 idx = cid[e];
        elist[j] = idx;
        rowflag[idx / KCLS] = 1u;
      }
    }
  }
}

// ---------------------------------------------- compact flagged rows to list
__global__ __launch_bounds__(256) void k_rowlist(
    const u32* __restrict__ rowflag, int* __restrict__ rowslot,
    u32* __restrict__ rowlist, int* __restrict__ rowcnt)
{
  int r = blockIdx.x * 256 + threadIdx.x;
  const int lane = threadIdx.x & 63;
  bool pred = (r < N_ROWS) && rowflag[r];
  u64 m = __ballot(pred);
  if (m) {
    int leader = __ffsll((long long)m) - 1;
    int base = 0;
    if (lane == leader) base = atomicAdd(rowcnt, (int)__popcll(m));
    base = __shfl(base, leader);
    if (pred) {
      int s = base + (int)__popcll(m & ((lane == 63) ? ~0ull >> 1 : ((1ull << lane) - 1)));
      if (s < ROWS_CAP) { rowslot[r] = s; rowlist[s] = (u32)r; }
    }
  }
}

// ---- exact f64 logits+softmax for flagged rows (RPB rows/block, coalesced w)
__global__ __launch_bounds__(128) void k_exact_rows(
    const u32* __restrict__ rowlist, const int* __restrict__ rowcnt,
    const float* __restrict__ x, const float* __restrict__ w,
    const float* __restrict__ bias, double* __restrict__ prow)
{
  __shared__ float xr[RPB][DIM];
  __shared__ double lg[RPB][KC1];
  __shared__ double mv[RPB], sv[RPB];
  int rc = *rowcnt; if (rc > ROWS_CAP) rc = ROWS_CAP;
  const int base = blockIdx.x * RPB;
  if (base >= rc) return;
  const int tid = threadIdx.x;
  const int nr = min(RPB, rc - base);

  for (int rr = 0; rr < nr; ++rr) {
    const float4* xs = (const float4*)(x + (size_t)rowlist[base + rr] * DIM);
    float4* dst = (float4*)xr[rr];
#pragma unroll
    for (int q = 0; q < DIM / 4 / 128; ++q) dst[tid + q * 128] = xs[tid + q * 128];
  }
  __syncthreads();

  if (tid < KC1) {
    const int c = tid;
    double a0 = 0.0, a1 = 0.0;
    for (int k = 0; k < DIM; k += 4) {
      float4 x0 = *(const float4*)&xr[0][k];
      float4 x1 = *(const float4*)&xr[1][k];
      float w0 = w[(size_t)k * KC1 + c];
      float w1 = w[(size_t)(k + 1) * KC1 + c];
      float w2 = w[(size_t)(k + 2) * KC1 + c];
      float w3 = w[(size_t)(k + 3) * KC1 + c];
      a0 = fma((double)x0.x, (double)w0, a0);
      a0 = fma((double)x0.y, (double)w1, a0);
      a0 = fma((double)x0.z, (double)w2, a0);
      a0 = fma((double)x0.w, (double)w3, a0);
      a1 = fma((double)x1.x, (double)w0, a1);
      a1 = fma((double)x1.y, (double)w1, a1);
      a1 = fma((double)x1.z, (double)w2, a1);
      a1 = fma((double)x1.w, (double)w3, a1);
    }
    lg[0][c] = a0 + (double)bias[c];
    lg[1][c] = a1 + (double)bias[c];
  }
  __syncthreads();
  if (tid < nr) {
    double m = -1e300;
    for (int c2 = 0; c2 < KC1; ++c2) m = fmax(m, lg[tid][c2]);
    mv[tid] = m;
  }
  __syncthreads();
  if (tid < KC1) {
    for (int rr = 0; rr < nr; ++rr) lg[rr][tid] = exp(lg[rr][tid] - mv[rr]);
  }
  __syncthreads();
  if (tid < nr) {
    double s = 0.0;
    for (int c2 = 0; c2 < KC1; ++c2) s += lg[tid][c2];
    sv[tid] = s;
  }
  __syncthreads();
  if (tid < KC1) {
    for (int rr = 0; rr < nr; ++rr)
      prow[(size_t)(base + rr) * KC1 + tid] = lg[rr][tid] / sv[rr];
  }
}

// ------------------------- build exact (score, idx) arrays for the superset
__global__ __launch_bounds__(256) void k_build(
    const u32* __restrict__ elist, const int* __restrict__ ecount,
    const int* __restrict__ rowslot, const double* __restrict__ prow,
    double* __restrict__ ssc, u32* __restrict__ sid)
{
  int E = *ecount; if (E > ECAP) E = ECAP;
  int e = blockIdx.x * 256 + threadIdx.x;
  if (e < E) {
    u32 idx = elist[e];
    int row = (int)(idx / KCLS);
    int cls = (int)(idx - (u32)row * KCLS);
    double p = prow[(size_t)rowslot[row] * KC1 + cls];
    ssc[e] = (p > SCORE_T) ? p : -1.0;
    sid[e] = idx;
  }
}

// --------------------------- exact rank-count among superset (j-range split)
__global__ __launch_bounds__(256) void k_rank(
    const double* __restrict__ ssc, const u32* __restrict__ sid,
    const int* __restrict__ ecount, int* __restrict__ cnt)
{
  __shared__ double lsc[2048];
  __shared__ u32 lid[2048];
  int S = *ecount; if (S > ECAP) S = ECAP;
  const int i = blockIdx.x * 256 + threadIdx.x;
  if (blockIdx.x * 256 >= S) return;
  const double si = (i < S) ? ssc[i] : -2.0;
  const u32 ii = (i < S) ? sid[i] : 0u;
  const int seg = (S + NSPLIT - 1) / NSPLIT;
  const int jlo = blockIdx.y * seg;
  const int jhi = min(S, jlo + seg);
  int c = 0;
  for (int base = jlo; base < jhi; base += 2048) {
    const int n = min(2048, jhi - base);
    __syncthreads();
    for (int e = threadIdx.x; e < n; e += 256) { lsc[e] = ssc[base + e]; lid[e] = sid[base + e]; }
    __syncthreads();
    if (i < S) {
      for (int j = 0; j < n; ++j) {
        double sj = lsc[j];
        c += (sj > si || (sj == si && lid[j] < ii)) ? 1 : 0;
      }
    }
  }
  if (i < S && c > 0) atomicAdd(&cnt[i], c);
}

// ----------------------------------------------------- scatter by final rank
__global__ __launch_bounds__(256) void k_scatter(
    const double* __restrict__ ssc, const u32* __restrict__ sid,
    const int* __restrict__ ecount, const int* __restrict__ cnt,
    double* __restrict__ selS, u32* __restrict__ selI)
{
  int S = *ecount; if (S > ECAP) S = ECAP;
  const int i = blockIdx.x * 256 + threadIdx.x;
  if (i < S) {
    int c = cnt[i];
    if (c < MCAND) { selS[c] = ssc[i]; selI[c] = sid[i]; }
  }
}

// -------------------------------- per-candidate bbox delta dot + decode + clip
__global__ __launch_bounds__(256) void k_gather_decode(
    const double* __restrict__ selS, const u32* __restrict__ selI,
    const float* __restrict__ x, const float* __restrict__ bw,
    const float* __restrict__ bbias, const float* __restrict__ proposals,
    float4* __restrict__ dbox, float4* __restrict__ obox,
    float* __restrict__ areav, float* __restrict__ scorev,
    int* __restrict__ clsv, int* __restrict__ validv)
{
  __shared__ double wred[4][4];
  const int r = blockIdx.x;
  const double s = selS[r];
  const u32 idx = selI[r];
  const int row = (int)(idx / 80u);
  const int cls = (int)(idx - (u32)row * 80u);

  const float* xr = x + (size_t)row * DIM;
  const float4* bwv = (const float4*)bw;
  double a0 = 0, a1 = 0, a2 = 0, a3 = 0;
  for (int k = threadIdx.x; k < DIM; k += 256) {
    double xv = (double)xr[k];
    float4 wv = bwv[(size_t)k * 80 + cls];
    a0 = fma(xv, (double)wv.x, a0);
    a1 = fma(xv, (double)wv.y, a1);
    a2 = fma(xv, (double)wv.z, a2);
    a3 = fma(xv, (double)wv.w, a3);
  }
#pragma unroll
  for (int off = 32; off > 0; off >>= 1) {
    a0 += __shfl_down(a0, off);
    a1 += __shfl_down(a1, off);
    a2 += __shfl_down(a2, off);
    a3 += __shfl_down(a3, off);
  }
  int lane = threadIdx.x & 63, wid = threadIdx.x >> 6;
  if (lane == 0) { wred[wid][0] = a0; wred[wid][1] = a1; wred[wid][2] = a2; wred[wid][3] = a3; }
  __syncthreads();
  if (threadIdx.x == 0) {
    double d0 = wred[0][0] + wred[1][0] + wred[2][0] + wred[3][0] + (double)bbias[cls * 4 + 0];
    double d1 = wred[0][1] + wred[1][1] + wred[2][1] + wred[3][1] + (double)bbias[cls * 4 + 1];
    double d2 = wred[0][2] + wred[1][2] + wred[2][2] + wred[3][2] + (double)bbias[cls * 4 + 2];
    double d3 = wred[0][3] + wred[1][3] + wred[2][3] + wred[3][3] + (double)bbias[cls * 4 + 3];
    float4 p = ((const float4*)proposals)[row];
    float w = p.z - p.x, h = p.w - p.y;
    float cxx = p.x + 0.5f * w, cyy = p.y + 0.5f * h;
    float dx = (float)d0 / 10.0f;
    float dy = (float)d1 / 10.0f;
    float dw = fminf((float)d2 / 5.0f, SCALE_CLAMP_F);
    float dh = fminf((float)d3 / 5.0f, SCALE_CLAMP_F);
    float pcx = dx * w + cxx, pcy = dy * h + cyy;
    float pw = expf(dw) * w, ph = expf(dh) * h;
    float x1 = pcx - 0.5f * pw, y1 = pcy - 0.5f * ph;
    float x2 = pcx + 0.5f * pw, y2 = pcy + 0.5f * ph;
    x1 = fminf(fmaxf(x1, 0.0f), IMG_W_F);
    x2 = fminf(fmaxf(x2, 0.0f), IMG_W_F);
    y1 = fminf(fmaxf(y1, 0.0f), IMG_H_F);
    y2 = fminf(fmaxf(y2, 0.0f), IMG_H_F);
    float4 db = {x1, y1, x2, y2};
    dbox[r] = db;
    float ofs = (float)cls * MAX_COORD_F;
    float4 ob = {x1 + ofs, y1 + ofs, x2 + ofs, y2 + ofs};
    obox[r] = ob;
    areav[r] = (ob.z - ob.x) * (ob.w - ob.y);
    scorev[r] = (float)s;
    clsv[r] = cls;
    validv[r] = (s > SCORE_T) ? 1 : 0;
  }
}

// --------------------- pairwise suppression bitmask (TRANSPOSED layout)
__global__ __launch_bounds__(256) void k_nms_mask(
    const float4* __restrict__ obox, const float* __restrict__ areav,
    u64* __restrict__ maskT)
{
  __shared__ float4 sb[MCAND];
  __shared__ float sa[MCAND];
  const int i = blockIdx.x;
  for (int e = threadIdx.x; e < MCAND; e += 256) { sb[e] = obox[e]; sa[e] = areav[e]; }
  __syncthreads();
  float4 bi = sb[i];
  float ai = sa[i];
  int lane = threadIdx.x & 63, wid = threadIdx.x >> 6;
#pragma unroll
  for (int it = 0; it < MCAND / 256; ++it) {
    int j = it * 256 + threadIdx.x;
    float4 bj = sb[j];
    float xx1 = fmaxf(bi.x, bj.x);
    float yy1 = fmaxf(bi.y, bj.y);
    float xx2 = fminf(bi.z, bj.z);
    float yy2 = fminf(bi.w, bj.w);
    float inter = fmaxf(xx2 - xx1, 0.0f) * fmaxf(yy2 - yy1, 0.0f);
    float uni = ai + sa[j] - inter;
    float iou = inter / fmaxf(uni, 1e-9f);
    bool pred = (iou > NMS_T) && (j > i);
    u64 b = __ballot(pred);
    if (lane == 0) maskT[(size_t)(it * 4 + wid) * MCAND + i] = b;
  }
}

// ---- sequential suppression scan: ONE wave, column-gather, EARLY EXIT at
// ---- 100 cumulative keeps (output only consumes the first 100 kept).
__global__ __launch_bounds__(64) void k_nms_reduce(
    const u64* __restrict__ maskT, const int* __restrict__ validv,
    int* __restrict__ keep)
{
  const int lane = threadIdx.x;  // 0..63

  // validw: lane k holds valid word k (k<32)
  u64 validw = 0;
  for (int k = 0; k < 32; ++k) {
    u64 b = __ballot(validv[k * 64 + lane] != 0);
    validw = (lane == k) ? b : validw;
  }

  u64 alivew = 0;   // lane k holds alive word k
  u64 supw = 0;     // lane k holds final sup word k
  int total = 0;
  int lastc = 31;

  for (int c = 0; c < 32; ++c) {
    const u64* col = maskT + (size_t)c * MCAND;
    // gather incoming suppression: alive rows i < 64c, column word c
    // fully-unrolled predicated batches so loads stay in registers and pipeline
    u64 acc = 0;
    for (int t0 = 0; t0 < c; t0 += 8) {
      u64 r0 = 0, r1 = 0, r2 = 0, r3 = 0, r4 = 0, r5 = 0, r6 = 0, r7 = 0;
      if (t0 + 0 < c) r0 = col[(t0 + 0) * 64 + lane];
      if (t0 + 1 < c) r1 = col[(t0 + 1) * 64 + lane];
      if (t0 + 2 < c) r2 = col[(t0 + 2) * 64 + lane];
      if (t0 + 3 < c) r3 = col[(t0 + 3) * 64 + lane];
      if (t0 + 4 < c) r4 = col[(t0 + 4) * 64 + lane];
      if (t0 + 5 < c) r5 = col[(t0 + 5) * 64 + lane];
      if (t0 + 6 < c) r6 = col[(t0 + 6) * 64 + lane];
      if (t0 + 7 < c) r7 = col[(t0 + 7) * 64 + lane];
      u64 a;
      a = readlane64(alivew, t0 + 0); acc |= r0 & ((u64)0 - ((a >> lane) & 1ull));
      if (t0 + 1 < c) { a = readlane64(alivew, t0 + 1); acc |= r1 & ((u64)0 - ((a >> lane) & 1ull)); }
      if (t0 + 2 < c) { a = readlane64(alivew, t0 + 2); acc |= r2 & ((u64)0 - ((a >> lane) & 1ull)); }
      if (t0 + 3 < c) { a = readlane64(alivew, t0 + 3); acc |= r3 & ((u64)0 - ((a >> lane) & 1ull)); }
      if (t0 + 4 < c) { a = readlane64(alivew, t0 + 4); acc |= r4 & ((u64)0 - ((a >> lane) & 1ull)); }
      if (t0 + 5 < c) { a = readlane64(alivew, t0 + 5); acc |= r5 & ((u64)0 - ((a >> lane) & 1ull)); }
      if (t0 + 6 < c) { a = readlane64(alivew, t0 + 6); acc |= r6 & ((u64)0 - ((a >> lane) & 1ull)); }
      if (t0 + 7 < c) { a = readlane64(alivew, t0 + 7); acc |= r7 & ((u64)0 - ((a >> lane) & 1ull)); }
    }
    u64 d = col[(size_t)c * 64 + lane];             // diagonal word (row 64c+lane)
    // OR-reduce acc across 64 lanes
    acc |= (u64)__shfl_xor((long long)acc, 1);
    acc |= (u64)__shfl_xor((long long)acc, 2);
    acc |= (u64)__shfl_xor((long long)acc, 4);
    acc |= (u64)__shfl_xor((long long)acc, 8);
    acc |= (u64)__shfl_xor((long long)acc, 16);
    acc |= (u64)__shfl_xor((long long)acc, 32);
    u64 s_sup = acc;                                 // wave-uniform now
    u64 s_val = readlane64(validw, c);
    // branch-free sequential intra-chunk resolve (row b has only bits > b)
    u64 aliveM = 0;
#pragma unroll
    for (int b = 0; b < 64; ++b) {
      u32 rhi = __builtin_amdgcn_readlane((u32)(d >> 32), b);
      u32 rlo = (b < 31) ? __builtin_amdgcn_readlane((u32)d, b) : 0u;
      u64 row = ((u64)rhi << 32) | (u64)rlo;
      u64 act = ((s_val >> b) & 1ull) & (~(s_sup >> b) & 1ull);
      s_sup |= row & ((u64)0 - act);
      aliveM |= act << b;
    }
    alivew = (lane == c) ? aliveM : alivew;
    supw   = (lane == c) ? s_sup  : supw;
    total += (int)__popcll(aliveM);
    if (total >= TOPK_) { lastc = c; break; }   // first TOPK_ keeps resolved
  }

  for (int k = 0; k < 32; ++k) {
    int e = k * 64 + lane;
    if (k <= lastc) {
      u64 s = readlane64(supw, k);
      int sb = (int)((s >> lane) & 1ull);
      keep[e] = (validv[e] && !sb) ? 1 : 0;
    } else {
      keep[e] = 0;   // never consumed: >=TOPK_ keeps exist in resolved prefix
    }
  }
}

// ------------------------------------------------ final top-100 + write outputs
__global__ __launch_bounds__(256) void k_finalize(
    const int* __restrict__ keep, const float4* __restrict__ dbox,
    const float* __restrict__ scorev, const int* __restrict__ clsv,
    float* __restrict__ out)
{
  __shared__ short fidx[TOPK_];
  __shared__ char ksh[MCAND];
  const int tid = threadIdx.x;
  for (int e = tid; e < MCAND; e += 256) ksh[e] = (char)keep[e];
  __syncthreads();
  if (tid == 0) {
    int cnt = 0;
    for (int r = 0; r < MCAND && cnt < TOPK_; ++r) if (ksh[r]) fidx[cnt++] = (short)r;
    for (int r = 0; r < MCAND && cnt < TOPK_; ++r) if (!ksh[r]) fidx[cnt++] = (short)r;
  }
  __syncthreads();
  if (tid < TOPK_) {
    int r = fidx[tid];
    float4 b = dbox[r];
    out[tid * 4 + 0] = b.x; out[tid * 4 + 1] = b.y;
    out[tid * 4 + 2] = b.z; out[tid * 4 + 3] = b.w;
    int kp = ksh[r];
    out[400 + tid] = kp ? scorev[r] : -1.0f;
    out[500 + tid] = (float)clsv[r];
    out[600 + tid] = kp ? 1.0f : 0.0f;
  }
}

// ----------------------------------------------------------------------------
extern "C" void kernel_launch(void* const* d_in, const int* in_sizes, int n_in,
                              void* d_out, int out_size, void* d_ws, size_t ws_size,
                              hipStream_t stream) {
  const float* x         = (const float*)d_in[0];
  const float* cls_w     = (const float*)d_in[1];
  const float* cls_b     = (const float*)d_in[2];
  const float* bbox_w    = (const float*)d_in[3];
  const float* bbox_b    = (const float*)d_in[4];
  const float* proposals = (const float*)d_in[5];
  float* out = (float*)d_out;

  char* ws = (char*)d_ws;
  size_t off = 0;
  float*  part  = (float*)(ws + off);  off += (size_t)KSPLIT * N_ROWS * KC1 * 4;
  float*  scf   = (float*)(ws + off);  off += (size_t)CMAX * 4;
  u32*    cid   = (u32*)(ws + off);    off += (size_t)CMAX * 4;
  int*    hist  = (int*)(ws + off);    off += (size_t)NBINS * 4;
  u32*    rowflag = (u32*)(ws + off);  off += (size_t)N_ROWS * 4;
  int*    rowslot = (int*)(ws + off);  off += (size_t)N_ROWS * 4;
  u32*    rowlist = (u32*)(ws + off);  off += (size_t)ROWS_CAP * 4;
  u32*    elist = (u32*)(ws + off);    off += (size_t)ECAP * 4;
  double* prow  = (double*)(ws + off); off += (size_t)ROWS_CAP * KC1 * 8;
  double* ssc   = (double*)(ws + off); off += (size_t)ECAP * 8;
  u32*    sid   = (u32*)(ws + off);    off += (size_t)ECAP * 4;
  int*    cnt   = (int*)(ws + off);    off += (size_t)ECAP * 4;
  double* selS  = (double*)(ws + off); off += (size_t)MCAND * 8;
  u32*    selI  = (u32*)(ws + off);    off += (size_t)MCAND * 4;
  off = (off + 15) & ~(size_t)15;
  int*    counter = (int*)(ws + off);  off += 16;
  int*    ecount  = (int*)(ws + off);  off += 16;
  int*    rowcnt  = (int*)(ws + off);  off += 16;
  int*    tbin    = (int*)(ws + off);  off += 16;
  float4* dbox  = (float4*)(ws + off); off += (size_t)MCAND * 16;
  float4* obox  = (float4*)(ws + off); off += (size_t)MCAND * 16;
  float*  areav = (float*)(ws + off);  off += (size_t)MCAND * 4;
  float*  scorev= (float*)(ws + off);  off += (size_t)MCAND * 4;
  int*    clsv  = (int*)(ws + off);    off += (size_t)MCAND * 4;
  int*    validv= (int*)(ws + off);    off += (size_t)MCAND * 4;
  int*    keep  = (int*)(ws + off);    off += (size_t)MCAND * 4;
  off = (off + 15) & ~(size_t)15;
  u64*    maskT = (u64*)(ws + off);    off += (size_t)MCAND * 32 * 8;

  k_init<<<N_ROWS / 256, 256, 0, stream>>>(counter, ecount, rowcnt, tbin, hist,
                                           cnt, rowflag, selS, selI);
  k_gemm_f32<<<dim3(N_ROWS / 32, KSPLIT), 256, 0, stream>>>(x, cls_w, part);
  k_softmax32<<<N_ROWS / 32, 256, 0, stream>>>(part, cls_b, scf, cid, counter, hist);
  k_thresh<<<1, 256, 0, stream>>>(hist, tbin);
  k_superset<<<CMAX / 256, 256, 0, stream>>>(scf, cid, counter, tbin, elist, ecount, rowflag);
  k_rowlist<<<N_ROWS / 256, 256, 0, stream>>>(rowflag, rowslot, rowlist, rowcnt);
  k_exact_rows<<<ROWS_CAP / RPB, 128, 0, stream>>>(rowlist, rowcnt, x, cls_w, cls_b, prow);
  k_build<<<ECAP / 256, 256, 0, stream>>>(elist, ecount, rowslot, prow, ssc, sid);
  k_rank<<<dim3(ECAP / 256, NSPLIT), 256, 0, stream>>>(ssc, sid, ecount, cnt);
  k_scatter<<<ECAP / 256, 256, 0, stream>>>(ssc, sid, ecount, cnt, selS, selI);
  k_gather_decode<<<MCAND, 256, 0, stream>>>(selS, selI, x, bbox_w, bbox_b, proposals,
                                             dbox, obox, areav, scorev, clsv, validv);
  k_nms_mask<<<MCAND, 256, 0, stream>>>(obox, areav, maskT);
  k_nms_reduce<<<1, 64, 0, stream>>>(maskT, validv, keep);
  k_finalize<<<1, 256, 0, stream>>>(keep, dbox, scorev, clsv, out);
}

// Round 13
// 281.451 us; speedup vs baseline: 1.8080x; 1.0356x over previous
//
#include <hip/hip_runtime.h>
#include <math.h>

typedef unsigned long long u64;
typedef unsigned int u32;

#define N_ROWS 8192
#define DIM 1024
#define KCLS 80
#define KC1 81
#define MCAND 2048
#define TOPK_ 100
#define CMAX 65536
#define ECAP 4096
#define ROWS_CAP 4096
#define RPB 2
#define KSPLIT 4
#define NSPLIT 4
#define NBINS 8192
#define BIN_BASE 125440
#define LCAP 1024
#define SCORE_T 0.05
#define NMS_T 0.5f
#define MAX_COORD_F 1217.0f
#define SCALE_CLAMP_F 4.135166556742356f
#define IMG_W_F 1216.0f
#define IMG_H_F 800.0f

__device__ __forceinline__ int score_bin_f(float p) {
  u32 bits = __float_as_uint(p);
  int b = (int)(bits >> 13) - BIN_BASE;
  return b < 0 ? 0 : (b > NBINS - 1 ? NBINS - 1 : b);
}

__device__ __forceinline__ u64 readlane64(u64 v, int l) {
  u32 lo = __builtin_amdgcn_readlane((u32)v, l);
  u32 hi = __builtin_amdgcn_readlane((u32)(v >> 32), l);
  return ((u64)hi << 32) | (u64)lo;
}

// ---------------------------------------------------------------- init
__global__ void k_init(int* counter, int* ecount, int* rowcnt, int* tbin,
                       int* hist, int* cnt, u32* rowflag,
                       double* selS, u32* selI) {
  int t = blockIdx.x * blockDim.x + threadIdx.x;
  if (t == 0) { *counter = 0; *ecount = 0; *rowcnt = 0; *tbin = 0; }
  if (t < NBINS) hist[t] = 0;
  if (t < N_ROWS) rowflag[t] = 0;
  if (t < ECAP) cnt[t] = 0;
  if (t < MCAND) { selS[t] = -1.0; selI[t] = 0u; }
}

// ------------------- transpose bbox_w: wT4[cls*1024 + k] = bw4[k*80 + cls]
__global__ __launch_bounds__(256) void k_bwt(const float4* __restrict__ bw4,
                                             float4* __restrict__ wT4) {
  int t = blockIdx.x * 256 + threadIdx.x;   // 0 .. 80*1024-1, coalesced read
  if (t < KCLS * DIM) {
    int k = t / KCLS;
    int cls = t - k * KCLS;
    wT4[(size_t)cls * DIM + k] = bw4[t];
  }
}

// --------------------------------- f32 cls GEMM, K split 4-way -> partials
// B tile staged as a contiguous 32x81 slab (flat), stride-81 reads.
#define BK 32
#define XT_STRIDE 34
#define BTN (BK * KC1)          // 2592

__global__ __launch_bounds__(256) void k_gemm_f32(
    const float* __restrict__ x, const float* __restrict__ w,
    float* __restrict__ part)
{
  __shared__ float xt[BK][XT_STRIDE];
  __shared__ float bt[BTN + 16];   // +16 pad: c>=81 garbage reads stay in-bounds

  const int tid = threadIdx.x;
  const int rb = blockIdx.x * 32;
  const int ks = blockIdx.y;
  const int koff = ks * (DIM / KSPLIT);
  const int cx = tid >> 4;
  const int ry = tid & 15;

  float acc[2][6];
#pragma unroll
  for (int i = 0; i < 2; i++)
#pragma unroll
    for (int j = 0; j < 6; j++) acc[i][j] = 0.0f;

  const int sr  = tid >> 3;
  const int skq = (tid & 7) * 4;

  for (int kt = 0; kt < DIM / KSPLIT; kt += BK) {
    const int kbase = koff + kt;
    float4 xv4 = *(const float4*)(x + (size_t)(rb + sr) * DIM + kbase + skq);
    // contiguous B slab: w + kbase*81, 2592 floats = 648 float4
    const float4* wsl = (const float4*)(w + (size_t)kbase * KC1);
    float4 b0, b1, b2;
    {
      int i0 = tid, i1 = tid + 256, i2 = tid + 512;
      b0 = wsl[i0];
      b1 = wsl[i1];
      if (i2 < BTN / 4) b2 = wsl[i2];
    }
    __syncthreads();
    xt[skq + 0][sr] = xv4.x; xt[skq + 1][sr] = xv4.y;
    xt[skq + 2][sr] = xv4.z; xt[skq + 3][sr] = xv4.w;
    {
      float4* bt4 = (float4*)bt;
      int i0 = tid, i1 = tid + 256, i2 = tid + 512;
      bt4[i0] = b0;
      bt4[i1] = b1;
      if (i2 < BTN / 4) bt4[i2] = b2;
    }
    __syncthreads();

#pragma unroll
    for (int k = 0; k < BK; ++k) {
      float2 xv = *(const float2*)&xt[k][ry * 2];
      const float* br = &bt[k * KC1 + cx * 6];
      float bd[6] = {br[0], br[1], br[2], br[3], br[4], br[5]};
#pragma unroll
      for (int j = 0; j < 6; j++) {
        acc[0][j] = fmaf(xv.x, bd[j], acc[0][j]);
        acc[1][j] = fmaf(xv.y, bd[j], acc[1][j]);
      }
    }
    __syncthreads();
  }

#pragma unroll
  for (int i = 0; i < 2; i++) {
    int r = rb + ry * 2 + i;
#pragma unroll
    for (int j = 0; j < 6; j++) {
      int c = cx * 6 + j;
      if (c < KC1) part[((size_t)ks * N_ROWS + r) * KC1 + c] = acc[i][j];
    }
  }
}

// ------------- f32 softmax + approx candidate compact + surely-valid hist
#define NE32 (32 * KC1)         // 2592 floats per slab-tile
__global__ __launch_bounds__(256) void k_softmax32(
    const float* __restrict__ part, const float* __restrict__ bias,
    float* __restrict__ scf, u32* __restrict__ cid,
    int* __restrict__ counter, int* __restrict__ hist)
{
  __shared__ float lgs[NE32];          // summed logits (pre-bias), 10.4 KB
  __shared__ float red[16][32];
  __shared__ float rowM[32];
  __shared__ float rowS[32];
  __shared__ u32 lhist[NBINS / 2];     // packed u16 pairs, 16 KB
  __shared__ float lscf[LCAP];         // 4 KB
  __shared__ u32 lcid[LCAP];           // 4 KB
  __shared__ int lcnt, gbase;
  const int tid = threadIdx.x;
  const int rb = blockIdx.x * 32;
  const int cx = tid >> 4;
  const int ry = tid & 15;

  if (tid == 0) lcnt = 0;
  for (int e = tid; e < NBINS / 2; e += 256) lhist[e] = 0u;

  {
    const float4* p0 = (const float4*)(part + ((size_t)0 * N_ROWS + rb) * KC1);
    const float4* p1 = (const float4*)(part + ((size_t)1 * N_ROWS + rb) * KC1);
    const float4* p2 = (const float4*)(part + ((size_t)2 * N_ROWS + rb) * KC1);
    const float4* p3 = (const float4*)(part + ((size_t)3 * N_ROWS + rb) * KC1);
    float4* dst = (float4*)lgs;
    for (int q = tid; q < NE32 / 4; q += 256) {
      float4 s0 = p0[q], s1 = p1[q], s2 = p2[q], s3 = p3[q];
      float4 t;
      t.x = (s0.x + s1.x) + (s2.x + s3.x);
      t.y = (s0.y + s1.y) + (s2.y + s3.y);
      t.z = (s0.z + s1.z) + (s2.z + s3.z);
      t.w = (s0.w + s1.w) + (s2.w + s3.w);
      dst[q] = t;
    }
  }
  __syncthreads();

  float lg[2][6];
#pragma unroll
  for (int i = 0; i < 2; i++) {
    int rloc = ry * 2 + i;
#pragma unroll
    for (int j = 0; j < 6; j++) {
      int c = cx * 6 + j;
      lg[i][j] = (c < KC1) ? (lgs[rloc * KC1 + c] + bias[c]) : -1e30f;
    }
  }
  float pm[2] = {-1e30f, -1e30f};
#pragma unroll
  for (int i = 0; i < 2; i++)
#pragma unroll
    for (int j = 0; j < 6; j++) pm[i] = fmaxf(pm[i], lg[i][j]);
  red[cx][ry * 2 + 0] = pm[0];
  red[cx][ry * 2 + 1] = pm[1];
  __syncthreads();
  if (tid < 32) {
    float m = -1e30f;
#pragma unroll
    for (int q = 0; q < 16; q++) m = fmaxf(m, red[q][tid]);
    rowM[tid] = m;
  }
  __syncthreads();
  float ps[2] = {0.0f, 0.0f};
#pragma unroll
  for (int i = 0; i < 2; i++) {
    float m = rowM[ry * 2 + i];
#pragma unroll
    for (int j = 0; j < 6; j++) {
      int c = cx * 6 + j;
      if (c < KC1) ps[i] += expf(lg[i][j] - m);
    }
  }
  __syncthreads();
  red[cx][ry * 2 + 0] = ps[0];
  red[cx][ry * 2 + 1] = ps[1];
  __syncthreads();
  if (tid < 32) {
    float s = 0.0f;
#pragma unroll
    for (int q = 0; q < 16; q++) s += red[q][tid];
    rowS[tid] = s;
  }
  __syncthreads();
#pragma unroll
  for (int i = 0; i < 2; i++) {
    int rloc = ry * 2 + i;
    float m = rowM[rloc], s = rowS[rloc];
#pragma unroll
    for (int j = 0; j < 6; j++) {
      int c = cx * 6 + j;
      if (c < KCLS) {
        float p = expf(lg[i][j] - m) / s;
        if (p > 0.0485f) {                     // superset of exact p>0.05
          int pos = atomicAdd(&lcnt, 1);       // LDS atomic (per-CU, fast)
          u32 idx = (u32)((rb + rloc) * KCLS + c);
          if (pos < LCAP) { lscf[pos] = p; lcid[pos] = idx; }
          else {                               // overflow fallback (rare)
            int g = atomicAdd(counter, 1);
            if (g < CMAX) { scf[g] = p; cid[g] = idx; }
          }
        }
        if (p > 0.051f) {                      // surely exact-valid
          int b = score_bin_f(p);
          atomicAdd(&lhist[b >> 1], 1u << ((b & 1) * 16));
        }
      }
    }
  }
  __syncthreads();
  if (tid == 0) {
    int n = min(lcnt, LCAP);
    gbase = atomicAdd(counter, n);
  }
  __syncthreads();
  {
    int n = min(lcnt, LCAP);
    for (int e = tid; e < n; e += 256) {
      int g = gbase + e;
      if (g < CMAX) { scf[g] = lscf[e]; cid[g] = lcid[e]; }
    }
  }
  for (int q = tid; q < NBINS / 2; q += 256) {
    u32 v = lhist[q];
    if (v) {
      u32 lo = v & 0xFFFFu, hi = v >> 16;
      if (lo) atomicAdd(&hist[q * 2 + 0], (int)lo);
      if (hi) atomicAdd(&hist[q * 2 + 1], (int)hi);
    }
  }
}

// -------------------------------------- find threshold bin (suffix >= MCAND)
__global__ __launch_bounds__(256) void k_thresh(
    const int* __restrict__ hist, int* __restrict__ tbin)
{
  __shared__ int h[NBINS];
  __shared__ int segsum[256];
  __shared__ int segsuf[256];
  const int tid = threadIdx.x;
  for (int e = tid; e < NBINS; e += 256) h[e] = hist[e];
  __syncthreads();
  int s = 0;
#pragma unroll
  for (int q = 0; q < NBINS / 256; ++q) s += h[tid * (NBINS / 256) + q];
  segsum[tid] = s;
  __syncthreads();
  if (tid == 0) {
    int run = 0;
    for (int t = 255; t >= 0; --t) { segsuf[t] = run; run += segsum[t]; }
  }
  __syncthreads();
  int run = segsuf[tid];
  if (run < MCAND) {
    const int lo = tid * (NBINS / 256);
    for (int b = lo + NBINS / 256 - 1; b >= lo; --b) {
      run += h[b];
      if (run >= MCAND) { *tbin = b; break; }
    }
  }
}

// -------------------- superset: approx-bin >= T-6 -> element list + row flags
__global__ __launch_bounds__(256) void k_superset(
    const float* __restrict__ scf, const u32* __restrict__ cid,
    const int* __restrict__ counter, const int* __restrict__ tbin,
    u32* __restrict__ elist, int* __restrict__ ecount, u32* __restrict__ rowflag)
{
  int C = *counter; if (C > CMAX) C = CMAX;
  int TM = *tbin - 6; if (TM < 0) TM = 0;
  int e = blockIdx.x * 256 + threadIdx.x;
  const int lane = threadIdx.x & 63;
  bool pred = false;
  float p = 0.0f;
  if (e < C) {
    p = scf[e];
    pred = (score_bin_f(p) >= TM);
  }
  u64 m = __ballot(pred);
  if (m) {
    int leader = __ffsll((long long)m) - 1;
    int base = 0;
    if (lane == leader) base = atomicAdd(ecount, (int)__popcll(m));
    base = __shfl(base, leader);
    if (pred) {
      int j = base + (int)__popcll(m & ((lane == 63) ? ~0ull >> 1 : ((1ull << lane) - 1)));
      if (j < ECAP) {
        u32 idx = cid[e];
        elist[j] = idx;
        rowflag[idx / KCLS] = 1u;
      }
    }
  }
}

// ---------------------------------------------- compact flagged rows to list
__global__ __launch_bounds__(256) void k_rowlist(
    const u32* __restrict__ rowflag, int* __restrict__ rowslot,
    u32* __restrict__ rowlist, int* __restrict__ rowcnt)
{
  int r = blockIdx.x * 256 + threadIdx.x;
  const int lane = threadIdx.x & 63;
  bool pred = (r < N_ROWS) && rowflag[r];
  u64 m = __ballot(pred);
  if (m) {
    int leader = __ffsll((long long)m) - 1;
    int base = 0;
    if (lane == leader) base = atomicAdd(rowcnt, (int)__popcll(m));
    base = __shfl(base, leader);
    if (pred) {
      int s = base + (int)__popcll(m & ((lane == 63) ? ~0ull >> 1 : ((1ull << lane) - 1)));
      if (s < ROWS_CAP) { rowslot[r] = s; rowlist[s] = (u32)r; }
    }
  }
}

// ---- exact f64 logits+softmax for flagged rows (RPB rows/block, coalesced w)
__global__ __launch_bounds__(128) void k_exact_rows(
    const u32* __restrict__ rowlist, const int* __restrict__ rowcnt,
    const float* __restrict__ x, const float* __restrict__ w,
    const float* __restrict__ bias, double* __restrict__ prow)
{
  __shared__ float xr[RPB][DIM];
  __shared__ double lg[RPB][KC1];
  __shared__ double mv[RPB], sv[RPB];
  int rc = *rowcnt; if (rc > ROWS_CAP) rc = ROWS_CAP;
  const int base = blockIdx.x * RPB;
  if (base >= rc) return;
  const int tid = threadIdx.x;
  const int nr = min(RPB, rc - base);

  for (int rr = 0; rr < nr; ++rr) {
    const float4* xs = (const float4*)(x + (size_t)rowlist[base + rr] * DIM);
    float4* dst = (float4*)xr[rr];
#pragma unroll
    for (int q = 0; q < DIM / 4 / 128; ++q) dst[tid + q * 128] = xs[tid + q * 128];
  }
  __syncthreads();

  if (tid < KC1) {
    const int c = tid;
    double a0 = 0.0, a1 = 0.0;
    for (int k = 0; k < DIM; k += 4) {
      float4 x0 = *(const float4*)&xr[0][k];
      float4 x1 = *(const float4*)&xr[1][k];
      float w0 = w[(size_t)k * KC1 + c];
      float w1 = w[(size_t)(k + 1) * KC1 + c];
      float w2 = w[(size_t)(k + 2) * KC1 + c];
      float w3 = w[(size_t)(k + 3) * KC1 + c];
      a0 = fma((double)x0.x, (double)w0, a0);
      a0 = fma((double)x0.y, (double)w1, a0);
      a0 = fma((double)x0.z, (double)w2, a0);
      a0 = fma((double)x0.w, (double)w3, a0);
      a1 = fma((double)x1.x, (double)w0, a1);
      a1 = fma((double)x1.y, (double)w1, a1);
      a1 = fma((double)x1.z, (double)w2, a1);
      a1 = fma((double)x1.w, (double)w3, a1);
    }
    lg[0][c] = a0 + (double)bias[c];
    lg[1][c] = a1 + (double)bias[c];
  }
  __syncthreads();
  if (tid < nr) {
    double m = -1e300;
    for (int c2 = 0; c2 < KC1; ++c2) m = fmax(m, lg[tid][c2]);
    mv[tid] = m;
  }
  __syncthreads();
  if (tid < KC1) {
    for (int rr = 0; rr < nr; ++rr) lg[rr][tid] = exp(lg[rr][tid] - mv[rr]);
  }
  __syncthreads();
  if (tid < nr) {
    double s = 0.0;
    for (int c2 = 0; c2 < KC1; ++c2) s += lg[tid][c2];
    sv[tid] = s;
  }
  __syncthreads();
  if (tid < KC1) {
    for (int rr = 0; rr < nr; ++rr)
      prow[(size_t)(base + rr) * KC1 + tid] = lg[rr][tid] / sv[rr];
  }
}

// ------------------------- build exact (score, idx) arrays for the superset
__global__ __launch_bounds__(256) void k_build(
    const u32* __restrict__ elist, const int* __restrict__ ecount,
    const int* __restrict__ rowslot, const double* __restrict__ prow,
    double* __restrict__ ssc, u32* __restrict__ sid)
{
  int E = *ecount; if (E > ECAP) E = ECAP;
  int e = blockIdx.x * 256 + threadIdx.x;
  if (e < E) {
    u32 idx = elist[e];
    int row = (int)(idx / KCLS);
    int cls = (int)(idx - (u32)row * KCLS);
    double p = prow[(size_t)rowslot[row] * KC1 + cls];
    ssc[e] = (p > SCORE_T) ? p : -1.0;
    sid[e] = idx;
  }
}

// --------------------------- exact rank-count among superset (j-range split)
__global__ __launch_bounds__(256) void k_rank(
    const double* __restrict__ ssc, const u32* __restrict__ sid,
    const int* __restrict__ ecount, int* __restrict__ cnt)
{
  __shared__ double lsc[2048];
  __shared__ u32 lid[2048];
  int S = *ecount; if (S > ECAP) S = ECAP;
  const int i = blockIdx.x * 256 + threadIdx.x;
  if (blockIdx.x * 256 >= S) return;
  const double si = (i < S) ? ssc[i] : -2.0;
  const u32 ii = (i < S) ? sid[i] : 0u;
  const int seg = (S + NSPLIT - 1) / NSPLIT;
  const int jlo = blockIdx.y * seg;
  const int jhi = min(S, jlo + seg);
  int c = 0;
  for (int base = jlo; base < jhi; base += 2048) {
    const int n = min(2048, jhi - base);
    __syncthreads();
    for (int e = threadIdx.x; e < n; e += 256) { lsc[e] = ssc[base + e]; lid[e] = sid[base + e]; }
    __syncthreads();
    if (i < S) {
      for (int j = 0; j < n; ++j) {
        double sj = lsc[j];
        c += (sj > si || (sj == si && lid[j] < ii)) ? 1 : 0;
      }
    }
  }
  if (i < S && c > 0) atomicAdd(&cnt[i], c);
}

// ----------------------------------------------------- scatter by final rank
__global__ __launch_bounds__(256) void k_scatter(
    const double* __restrict__ ssc, const u32* __restrict__ sid,
    const int* __restrict__ ecount, const int* __restrict__ cnt,
    double* __restrict__ selS, u32* __restrict__ selI)
{
  int S = *ecount; if (S > ECAP) S = ECAP;
  const int i = blockIdx.x * 256 + threadIdx.x;
  if (i < S) {
    int c = cnt[i];
    if (c < MCAND) { selS[c] = ssc[i]; selI[c] = sid[i]; }
  }
}

// ---- per-candidate bbox delta dot + decode + clip (coalesced via wT4)
__global__ __launch_bounds__(256) void k_gather_decode(
    const double* __restrict__ selS, const u32* __restrict__ selI,
    const float* __restrict__ x, const float4* __restrict__ wT4,
    const float* __restrict__ bbias, const float* __restrict__ proposals,
    float4* __restrict__ dbox, float4* __restrict__ obox,
    float* __restrict__ areav, float* __restrict__ scorev,
    int* __restrict__ clsv, int* __restrict__ validv)
{
  __shared__ double wred[4][4];
  const int r = blockIdx.x;
  const double s = selS[r];
  const u32 idx = selI[r];
  const int row = (int)(idx / 80u);
  const int cls = (int)(idx - (u32)row * 80u);

  const float* xr = x + (size_t)row * DIM;
  const float4* wc = wT4 + (size_t)cls * DIM;   // contiguous per-class slab
  double a0 = 0, a1 = 0, a2 = 0, a3 = 0;
  for (int k = threadIdx.x; k < DIM; k += 256) {
    double xv = (double)xr[k];
    float4 wv = wc[k];
    a0 = fma(xv, (double)wv.x, a0);
    a1 = fma(xv, (double)wv.y, a1);
    a2 = fma(xv, (double)wv.z, a2);
    a3 = fma(xv, (double)wv.w, a3);
  }
#pragma unroll
  for (int off = 32; off > 0; off >>= 1) {
    a0 += __shfl_down(a0, off);
    a1 += __shfl_down(a1, off);
    a2 += __shfl_down(a2, off);
    a3 += __shfl_down(a3, off);
  }
  int lane = threadIdx.x & 63, wid = threadIdx.x >> 6;
  if (lane == 0) { wred[wid][0] = a0; wred[wid][1] = a1; wred[wid][2] = a2; wred[wid][3] = a3; }
  __syncthreads();
  if (threadIdx.x == 0) {
    double d0 = wred[0][0] + wred[1][0] + wred[2][0] + wred[3][0] + (double)bbias[cls * 4 + 0];
    double d1 = wred[0][1] + wred[1][1] + wred[2][1] + wred[3][1] + (double)bbias[cls * 4 + 1];
    double d2 = wred[0][2] + wred[1][2] + wred[2][2] + wred[3][2] + (double)bbias[cls * 4 + 2];
    double d3 = wred[0][3] + wred[1][3] + wred[2][3] + wred[3][3] + (double)bbias[cls * 4 + 3];
    float4 p = ((const float4*)proposals)[row];
    float w = p.z - p.x, h = p.w - p.y;
    float cxx = p.x + 0.5f * w, cyy = p.y + 0.5f * h;
    float dx = (float)d0 / 10.0f;
    float dy = (float)d1 / 10.0f;
    float dw = fminf((float)d2 / 5.0f, SCALE_CLAMP_F);
    float dh = fminf((float)d3 / 5.0f, SCALE_CLAMP_F);
    float pcx = dx * w + cxx, pcy = dy * h + cyy;
    float pw = expf(dw) * w, ph = expf(dh) * h;
    float x1 = pcx - 0.5f * pw, y1 = pcy - 0.5f * ph;
    float x2 = pcx + 0.5f * pw, y2 = pcy + 0.5f * ph;
    x1 = fminf(fmaxf(x1, 0.0f), IMG_W_F);
    x2 = fminf(fmaxf(x2, 0.0f), IMG_W_F);
    y1 = fminf(fmaxf(y1, 0.0f), IMG_H_F);
    y2 = fminf(fmaxf(y2, 0.0f), IMG_H_F);
    float4 db = {x1, y1, x2, y2};
    dbox[r] = db;
    float ofs = (float)cls * MAX_COORD_F;
    float4 ob = {x1 + ofs, y1 + ofs, x2 + ofs, y2 + ofs};
    obox[r] = ob;
    areav[r] = (ob.z - ob.x) * (ob.w - ob.y);
    scorev[r] = (float)s;
    clsv[r] = cls;
    validv[r] = (s > SCORE_T) ? 1 : 0;
  }
}

// --------------------- pairwise suppression bitmask (TRANSPOSED layout)
__global__ __launch_bounds__(256) void k_nms_mask(
    const float4* __restrict__ obox, const float* __restrict__ areav,
    u64* __restrict__ maskT)
{
  __shared__ float4 sb[MCAND];
  __shared__ float sa[MCAND];
  const int i = blockIdx.x;
  for (int e = threadIdx.x; e < MCAND; e += 256) { sb[e] = obox[e]; sa[e] = areav[e]; }
  __syncthreads();
  float4 bi = sb[i];
  float ai = sa[i];
  int lane = threadIdx.x & 63, wid = threadIdx.x >> 6;
#pragma unroll
  for (int it = 0; it < MCAND / 256; ++it) {
    int j = it * 256 + threadIdx.x;
    float4 bj = sb[j];
    float xx1 = fmaxf(bi.x, bj.x);
    float yy1 = fmaxf(bi.y, bj.y);
    float xx2 = fminf(bi.z, bj.z);
    float yy2 = fminf(bi.w, bj.w);
    float inter = fmaxf(xx2 - xx1, 0.0f) * fmaxf(yy2 - yy1, 0.0f);
    float uni = ai + sa[j] - inter;
    float iou = inter / fmaxf(uni, 1e-9f);
    bool pred = (iou > NMS_T) && (j > i);
    u64 b = __ballot(pred);
    if (lane == 0) maskT[(size_t)(it * 4 + wid) * MCAND + i] = b;
  }
}

// ---- sequential suppression scan: ONE wave, column-gather, EARLY EXIT at
// ---- 100 cumulative keeps (output only consumes the first 100 kept).
__global__ __launch_bounds__(64) void k_nms_reduce(
    const u64* __restrict__ maskT, const int* __restrict__ validv,
    int* __restrict__ keep)
{
  const int lane = threadIdx.x;  // 0..63

  u64 validw = 0;
  for (int k = 0; k < 32; ++k) {
    u64 b = __ballot(validv[k * 64 + lane] != 0);
    validw = (lane == k) ? b : validw;
  }

  u64 alivew = 0;
  u64 supw = 0;
  int total = 0;
  int lastc = 31;

  for (int c = 0; c < 32; ++c) {
    const u64* col = maskT + (size_t)c * MCAND;
    u64 acc = 0;
    for (int t0 = 0; t0 < c; t0 += 8) {
      u64 r0 = 0, r1 = 0, r2 = 0, r3 = 0, r4 = 0, r5 = 0, r6 = 0, r7 = 0;
      if (t0 + 0 < c) r0 = col[(t0 + 0) * 64 + lane];
      if (t0 + 1 < c) r1 = col[(t0 + 1) * 64 + lane];
      if (t0 + 2 < c) r2 = col[(t0 + 2) * 64 + lane];
      if (t0 + 3 < c) r3 = col[(t0 + 3) * 64 + lane];
      if (t0 + 4 < c) r4 = col[(t0 + 4) * 64 + lane];
      if (t0 + 5 < c) r5 = col[(t0 + 5) * 64 + lane];
      if (t0 + 6 < c) r6 = col[(t0 + 6) * 64 + lane];
      if (t0 + 7 < c) r7 = col[(t0 + 7) * 64 + lane];
      u64 a;
      a = readlane64(alivew, t0 + 0); acc |= r0 & ((u64)0 - ((a >> lane) & 1ull));
      if (t0 + 1 < c) { a = readlane64(alivew, t0 + 1); acc |= r1 & ((u64)0 - ((a >> lane) & 1ull)); }
      if (t0 + 2 < c) { a = readlane64(alivew, t0 + 2); acc |= r2 & ((u64)0 - ((a >> lane) & 1ull)); }
      if (t0 + 3 < c) { a = readlane64(alivew, t0 + 3); acc |= r3 & ((u64)0 - ((a >> lane) & 1ull)); }
      if (t0 + 4 < c) { a = readlane64(alivew, t0 + 4); acc |= r4 & ((u64)0 - ((a >> lane) & 1ull)); }
      if (t0 + 5 < c) { a = readlane64(alivew, t0 + 5); acc |= r5 & ((u64)0 - ((a >> lane) & 1ull)); }
      if (t0 + 6 < c) { a = readlane64(alivew, t0 + 6); acc |= r6 & ((u64)0 - ((a >> lane) & 1ull)); }
      if (t0 + 7 < c) { a = readlane64(alivew, t0 + 7); acc |= r7 & ((u64)0 - ((a >> lane) & 1ull)); }
    }
    u64 d = col[(size_t)c * 64 + lane];
    acc |= (u64)__shfl_xor((long long)acc, 1);
    acc |= (u64)__shfl_xor((long long)acc, 2);
    acc |= (u64)__shfl_xor((long long)acc, 4);
    acc |= (u64)__shfl_xor((long long)acc, 8);
    acc |= (u64)__shfl_xor((long long)acc, 16);
    acc |= (u64)__shfl_xor((long long)acc, 32);
    u64 s_sup = acc;
    u64 s_val = readlane64(validw, c);
    u64 aliveM = 0;
#pragma unroll
    for (int b = 0; b < 64; ++b) {
      u32 rhi = __builtin_amdgcn_readlane((u32)(d >> 32), b);
      u32 rlo = (b < 31) ? __builtin_amdgcn_readlane((u32)d, b) : 0u;
      u64 row = ((u64)rhi << 32) | (u64)rlo;
      u64 act = ((s_val >> b) & 1ull) & (~(s_sup >> b) & 1ull);
      s_sup |= row & ((u64)0 - act);
      aliveM |= act << b;
    }
    alivew = (lane == c) ? aliveM : alivew;
    supw   = (lane == c) ? s_sup  : supw;
    total += (int)__popcll(aliveM);
    if (total >= TOPK_) { lastc = c; break; }
  }

  for (int k = 0; k < 32; ++k) {
    int e = k * 64 + lane;
    if (k <= lastc) {
      u64 s = readlane64(supw, k);
      int sb = (int)((s >> lane) & 1ull);
      keep[e] = (validv[e] && !sb) ? 1 : 0;
    } else {
      keep[e] = 0;
    }
  }
}

// ------------------------------------------------ final top-100 + write outputs
__global__ __launch_bounds__(256) void k_finalize(
    const int* __restrict__ keep, const float4* __restrict__ dbox,
    const float* __restrict__ scorev, const int* __restrict__ clsv,
    float* __restrict__ out)
{
  __shared__ short fidx[TOPK_];
  __shared__ char ksh[MCAND];
  const int tid = threadIdx.x;
  for (int e = tid; e < MCAND; e += 256) ksh[e] = (char)keep[e];
  __syncthreads();
  if (tid == 0) {
    int cnt = 0;
    for (int r = 0; r < MCAND && cnt < TOPK_; ++r) if (ksh[r]) fidx[cnt++] = (short)r;
    for (int r = 0; r < MCAND && cnt < TOPK_; ++r) if (!ksh[r]) fidx[cnt++] = (short)r;
  }
  __syncthreads();
  if (tid < TOPK_) {
    int r = fidx[tid];
    float4 b = dbox[r];
    out[tid * 4 + 0] = b.x; out[tid * 4 + 1] = b.y;
    out[tid * 4 + 2] = b.z; out[tid * 4 + 3] = b.w;
    int kp = ksh[r];
    out[400 + tid] = kp ? scorev[r] : -1.0f;
    out[500 + tid] = (float)clsv[r];
    out[600 + tid] = kp ? 1.0f : 0.0f;
  }
}

// ----------------------------------------------------------------------------
extern "C" void kernel_launch(void* const* d_in, const int* in_sizes, int n_in,
                              void* d_out, int out_size, void* d_ws, size_t ws_size,
                              hipStream_t stream) {
  const float* x         = (const float*)d_in[0];
  const float* cls_w     = (const float*)d_in[1];
  const float* cls_b     = (const float*)d_in[2];
  const float* bbox_w    = (const float*)d_in[3];
  const float* bbox_b    = (const float*)d_in[4];
  const float* proposals = (const float*)d_in[5];
  float* out = (float*)d_out;

  char* ws = (char*)d_ws;
  size_t off = 0;
  float*  part  = (float*)(ws + off);  off += (size_t)KSPLIT * N_ROWS * KC1 * 4;
  float4* wT4   = (float4*)(ws + off); off += (size_t)KCLS * DIM * 16;   // 1.31 MB
  float*  scf   = (float*)(ws + off);  off += (size_t)CMAX * 4;
  u32*    cid   = (u32*)(ws + off);    off += (size_t)CMAX * 4;
  int*    hist  = (int*)(ws + off);    off += (size_t)NBINS * 4;
  u32*    rowflag = (u32*)(ws + off);  off += (size_t)N_ROWS * 4;
  int*    rowslot = (int*)(ws + off);  off += (size_t)N_ROWS * 4;
  u32*    rowlist = (u32*)(ws + off);  off += (size_t)ROWS_CAP * 4;
  u32*    elist = (u32*)(ws + off);    off += (size_t)ECAP * 4;
  double* prow  = (double*)(ws + off); off += (size_t)ROWS_CAP * KC1 * 8;
  double* ssc   = (double*)(ws + off); off += (size_t)ECAP * 8;
  u32*    sid   = (u32*)(ws + off);    off += (size_t)ECAP * 4;
  int*    cnt   = (int*)(ws + off);    off += (size_t)ECAP * 4;
  double* selS  = (double*)(ws + off); off += (size_t)MCAND * 8;
  u32*    selI  = (u32*)(ws + off);    off += (size_t)MCAND * 4;
  off = (off + 15) & ~(size_t)15;
  int*    counter = (int*)(ws + off);  off += 16;
  int*    ecount  = (int*)(ws + off);  off += 16;
  int*    rowcnt  = (int*)(ws + off);  off += 16;
  int*    tbin    = (int*)(ws + off);  off += 16;
  float4* dbox  = (float4*)(ws + off); off += (size_t)MCAND * 16;
  float4* obox  = (float4*)(ws + off); off += (size_t)MCAND * 16;
  float*  areav = (float*)(ws + off);  off += (size_t)MCAND * 4;
  float*  scorev= (float*)(ws + off);  off += (size_t)MCAND * 4;
  int*    clsv  = (int*)(ws + off);    off += (size_t)MCAND * 4;
  int*    validv= (int*)(ws + off);    off += (size_t)MCAND * 4;
  int*    keep  = (int*)(ws + off);    off += (size_t)MCAND * 4;
  off = (off + 15) & ~(size_t)15;
  u64*    maskT = (u64*)(ws + off);    off += (size_t)MCAND * 32 * 8;

  k_init<<<N_ROWS / 256, 256, 0, stream>>>(counter, ecount, rowcnt, tbin, hist,
                                           cnt, rowflag, selS, selI);
  k_bwt<<<(KCLS * DIM + 255) / 256, 256, 0, stream>>>((const float4*)bbox_w, wT4);
  k_gemm_f32<<<dim3(N_ROWS / 32, KSPLIT), 256, 0, stream>>>(x, cls_w, part);
  k_softmax32<<<N_ROWS / 32, 256, 0, stream>>>(part, cls_b, scf, cid, counter, hist);
  k_thresh<<<1, 256, 0, stream>>>(hist, tbin);
  k_superset<<<CMAX / 256, 256, 0, stream>>>(scf, cid, counter, tbin, elist, ecount, rowflag);
  k_rowlist<<<N_ROWS / 256, 256, 0, stream>>>(rowflag, rowslot, rowlist, rowcnt);
  k_exact_rows<<<ROWS_CAP / RPB, 128, 0, stream>>>(rowlist, rowcnt, x, cls_w, cls_b, prow);
  k_build<<<ECAP / 256, 256, 0, stream>>>(elist, ecount, rowslot, prow, ssc, sid);
  k_rank<<<dim3(ECAP / 256, NSPLIT), 256, 0, stream>>>(ssc, sid, ecount, cnt);
  k_scatter<<<ECAP / 256, 256, 0, stream>>>(ssc, sid, ecount, cnt, selS, selI);
  k_gather_decode<<<MCAND, 256, 0, stream>>>(selS, selI, x, wT4, bbox_b, proposals,
                                             dbox, obox, areav, scorev, clsv, validv);
  k_nms_mask<<<MCAND, 256, 0, stream>>>(obox, areav, maskT);
  k_nms_reduce<<<1, 64, 0, stream>>>(maskT, validv, keep);
  k_finalize<<<1, 256, 0, stream>>>(keep, dbox, scorev, clsv, out);
}